// Round 1
// baseline (43082.361 us; speedup 1.0000x reference)
//
#include <hip/hip_runtime.h>
#include <hip/hip_cooperative_groups.h>

namespace cg = cooperative_groups;

#define BB    128     // batch
#define TSEQ  256     // time steps
#define DH    1024    // hidden
#define DK2   2048    // concat K
#define NWG   256
#define NTHR  512

typedef __attribute__((ext_vector_type(8))) short short8;
typedef __attribute__((ext_vector_type(4))) float f32x4;

__device__ __forceinline__ unsigned short f2bf(float f) {
    union { float f; unsigned int u; } v; v.f = f;
    unsigned int r = (v.u + 0x7FFFu + ((v.u >> 16) & 1u)) >> 16;  // RNE
    return (unsigned short)r;
}

// ---------------- weight prep: transpose f32 [K][N] -> bf16 [N][K] (+fold for L2 f,i) ----------------
__global__ __launch_bounds__(256) void prep_weights(const float* __restrict__ W0,
                                                    const float* __restrict__ W1,
                                                    unsigned short* W0f, unsigned short* W0i,
                                                    unsigned short* W0z, unsigned short* Wff,
                                                    unsigned short* Wii, unsigned short* W1z) {
    __shared__ float tl[32][33];
    const int tx = threadIdx.x & 31, ty = threadIdx.x >> 5;  // ty 0..7
    int job = blockIdx.x;
    if (job < 6144) {                       // W0 gates: 3 x [2048 x 1024] transpose
        int g = job >> 11, r = job & 2047, kt = r >> 5, nt = r & 31;
        const float* src = W0 + (size_t)g * DK2 * DH;
        unsigned short* dst = (g == 0) ? W0f : ((g == 1) ? W0i : W0z);
        #pragma unroll
        for (int i = 0; i < 4; ++i)
            tl[ty + i * 8][tx] = src[(size_t)(kt * 32 + ty + i * 8) * DH + nt * 32 + tx];
        __syncthreads();
        #pragma unroll
        for (int i = 0; i < 4; ++i)
            dst[(size_t)(nt * 32 + ty + i * 8) * DK2 + kt * 32 + tx] = f2bf(tl[tx][ty + i * 8]);
    } else if (job < 8192) {                // W1 f,i folded: [1024][1024], dst[n][k]=W1[g][k][n]+W1[g][k+1024][n]
        int r = job - 6144; int g = r >> 10; r &= 1023;
        int kt = r >> 5, nt = r & 31;
        const float* src = W1 + (size_t)g * DK2 * DH;
        unsigned short* dst = (g == 0) ? Wff : Wii;
        #pragma unroll
        for (int i = 0; i < 4; ++i)
            tl[ty + i * 8][tx] = src[(size_t)(kt * 32 + ty + i * 8) * DH + nt * 32 + tx]
                               + src[(size_t)(1024 + kt * 32 + ty + i * 8) * DH + nt * 32 + tx];
        __syncthreads();
        #pragma unroll
        for (int i = 0; i < 4; ++i)
            dst[(size_t)(nt * 32 + ty + i * 8) * DH + kt * 32 + tx] = f2bf(tl[tx][ty + i * 8]);
    } else {                                // W1 z: [2048 x 1024] transpose
        int r = job - 8192; int kt = r >> 5, nt = r & 31;
        const float* src = W1 + (size_t)2 * DK2 * DH;
        #pragma unroll
        for (int i = 0; i < 4; ++i)
            tl[ty + i * 8][tx] = src[(size_t)(kt * 32 + ty + i * 8) * DH + nt * 32 + tx];
        __syncthreads();
        #pragma unroll
        for (int i = 0; i < 4; ++i)
            W1z[(size_t)(nt * 32 + ty + i * 8) * DK2 + kt * 32 + tx] = f2bf(tl[tx][ty + i * 8]);
    }
}

// ---------------- main persistent kernel ----------------
struct GruParams {
    const float* x;                 // [128][256][1024] f32
    const float* b0;                // [3][1024]
    const float* b1;                // [3][1024]
    const unsigned short* W0f;      // [1024 n][2048 k]  (k<1024: x-part, k>=1024: h-part)
    const unsigned short* W0i;
    const unsigned short* W0z;
    const unsigned short* Wff;      // [1024][1024] folded
    const unsigned short* Wii;
    const unsigned short* W1z;      // [1024 n][2048 k]  (k<1024: h1-part, k>=1024: h1*i2-part)
    float* xpre;                    // [32][128][3072] f32 chunk of x-part preacts
    float* h;  unsigned short* hb;  // h master f32 + bf16
    float* fg;                      // L1 f gate f32
    unsigned short* hib;            // h*i bf16
    float* h1; unsigned short* h1b;
    float* f2g;
    unsigned short* h1i2b;
    float* zx;                      // L2 z x-part preact (incl bias)
    float* out;
};

__device__ __forceinline__ f32x4 mm16(const unsigned short* __restrict__ ap,
                                      const unsigned short* __restrict__ wp, int iters) {
    f32x4 acc = {0.f, 0.f, 0.f, 0.f};
    #pragma unroll 4
    for (int k = 0; k < iters; ++k) {
        short8 a = *(const short8*)ap;
        short8 b = *(const short8*)wp;
        ap += 32; wp += 32;
        acc = __builtin_amdgcn_mfma_f32_16x16x32_bf16(a, b, acc, 0, 0, 0);
    }
    return acc;
}

__global__ __launch_bounds__(NTHR) void gru_main(GruParams P) {
    cg::grid_group grid = cg::this_grid();
    const int wg   = blockIdx.x;
    const int tid  = threadIdx.x;
    const int lane = tid & 63;
    const int wv   = tid >> 6;         // 0..7
    const int tile = wv & 3, ks = wv >> 2;
    const int lr   = lane & 15;
    const int kb   = (lane >> 4) * 8;  // k-offset within frag
    const int drow = (lane >> 4) * 4;  // D-frag row base

    __shared__ float s_red[4][16][16];

    // init h = 0
    for (int idx = wg * NTHR + tid; idx < BB * DH; idx += NWG * NTHR) {
        P.h[idx] = 0.f; P.hb[idx] = 0;
    }
    grid.sync();

    for (int t = 0; t < TSEQ; ++t) {
        // ---- chunk GEMM every 32 steps: xpre[tt][b][g*1024+n] = x[b][t+tt] @ W0[g][:1024] ----
        if ((t & 31) == 0) {
            for (int j = wg; j < 1536; j += NWG) {
                int mb = j / 48, nj = j % 48;          // mb = tt, 64 cols per job
                int b = wv * 16 + lr;
                const float* xp = P.x + ((size_t)b * TSEQ + (t + mb)) * DH + kb;
                int cbase = nj * 64;
                int g = cbase >> 10, nb0 = cbase & 1023;
                const unsigned short* wt = (g == 0) ? P.W0f : ((g == 1) ? P.W0i : P.W0z);
                const unsigned short* wp = wt + (size_t)(nb0 + lr) * DK2 + kb;
                f32x4 a0 = {0,0,0,0}, a1 = a0, a2 = a0, a3 = a0;
                #pragma unroll 2
                for (int k = 0; k < DH; k += 32) {
                    f32x4 lo = *(const f32x4*)(xp + k);
                    f32x4 hi = *(const f32x4*)(xp + k + 4);
                    short8 av;
                    av[0] = (short)f2bf(lo[0]); av[1] = (short)f2bf(lo[1]);
                    av[2] = (short)f2bf(lo[2]); av[3] = (short)f2bf(lo[3]);
                    av[4] = (short)f2bf(hi[0]); av[5] = (short)f2bf(hi[1]);
                    av[6] = (short)f2bf(hi[2]); av[7] = (short)f2bf(hi[3]);
                    short8 b0v = *(const short8*)(wp + k);
                    short8 b1v = *(const short8*)(wp + (size_t)16 * DK2 + k);
                    short8 b2v = *(const short8*)(wp + (size_t)32 * DK2 + k);
                    short8 b3v = *(const short8*)(wp + (size_t)48 * DK2 + k);
                    a0 = __builtin_amdgcn_mfma_f32_16x16x32_bf16(av, b0v, a0, 0, 0, 0);
                    a1 = __builtin_amdgcn_mfma_f32_16x16x32_bf16(av, b1v, a1, 0, 0, 0);
                    a2 = __builtin_amdgcn_mfma_f32_16x16x32_bf16(av, b2v, a2, 0, 0, 0);
                    a3 = __builtin_amdgcn_mfma_f32_16x16x32_bf16(av, b3v, a3, 0, 0, 0);
                }
                int rowb = mb * 128 + wv * 16 + drow;
                #pragma unroll
                for (int cf = 0; cf < 4; ++cf) {
                    f32x4 acc = (cf == 0) ? a0 : ((cf == 1) ? a1 : ((cf == 2) ? a2 : a3));
                    int col = cbase + cf * 16 + lr;
                    #pragma unroll
                    for (int rr = 0; rr < 4; ++rr)
                        P.xpre[(size_t)(rowb + rr) * 3072 + col] = acc[rr];
                }
            }
            grid.sync();
        }
        const int tq = t & 31;

        // ---- Phase A: L1 f,i = sigmoid(xpre + h @ W0{f,i}[h-part] + b0) ----
        {
            int g = wg >> 7, r = wg & 127, mb = r >> 5, nb = r & 31;
            const unsigned short* wt = (g == 0) ? P.W0f : P.W0i;
            int wm = tile >> 1, wn = tile & 1;
            int rowb = mb * 32 + wm * 16, colb = nb * 32 + wn * 16;
            const unsigned short* ap = P.hb + (size_t)(rowb + lr) * DH + ks * 512 + kb;
            const unsigned short* wp = wt + (size_t)(colb + lr) * DK2 + 1024 + ks * 512 + kb;
            f32x4 acc = mm16(ap, wp, 16);
            __syncthreads();
            if (ks == 1) {
                s_red[tile][drow + 0][lr] = acc[0]; s_red[tile][drow + 1][lr] = acc[1];
                s_red[tile][drow + 2][lr] = acc[2]; s_red[tile][drow + 3][lr] = acc[3];
            }
            __syncthreads();
            if (ks == 0) {
                acc[0] += s_red[tile][drow + 0][lr]; acc[1] += s_red[tile][drow + 1][lr];
                acc[2] += s_red[tile][drow + 2][lr]; acc[3] += s_red[tile][drow + 3][lr];
                #pragma unroll
                for (int rr = 0; rr < 4; ++rr) {
                    int b = rowb + drow + rr, n = colb + lr;
                    float pre = acc[rr] + P.xpre[(size_t)(tq * 128 + b) * 3072 + g * DH + n]
                              + P.b0[g * DH + n];
                    float s = 1.f / (1.f + __expf(-pre));
                    if (g == 0) P.fg[(size_t)b * DH + n] = s;
                    else        P.hib[(size_t)b * DH + n] = f2bf(P.h[(size_t)b * DH + n] * s);
                }
            }
        }
        grid.sync();

        // ---- Phase B: L1 z = tanh(xpre_z + (h*i) @ W0z[h-part] + b0z); h1 = (1-f)h + f z ----
        if (wg < 128) {
            int mb = wg >> 5, nb = wg & 31;
            int wm = tile >> 1, wn = tile & 1;
            int rowb = mb * 32 + wm * 16, colb = nb * 32 + wn * 16;
            const unsigned short* ap = P.hib + (size_t)(rowb + lr) * DH + ks * 512 + kb;
            const unsigned short* wp = P.W0z + (size_t)(colb + lr) * DK2 + 1024 + ks * 512 + kb;
            f32x4 acc = mm16(ap, wp, 16);
            __syncthreads();
            if (ks == 1) {
                s_red[tile][drow + 0][lr] = acc[0]; s_red[tile][drow + 1][lr] = acc[1];
                s_red[tile][drow + 2][lr] = acc[2]; s_red[tile][drow + 3][lr] = acc[3];
            }
            __syncthreads();
            if (ks == 0) {
                acc[0] += s_red[tile][drow + 0][lr]; acc[1] += s_red[tile][drow + 1][lr];
                acc[2] += s_red[tile][drow + 2][lr]; acc[3] += s_red[tile][drow + 3][lr];
                #pragma unroll
                for (int rr = 0; rr < 4; ++rr) {
                    int b = rowb + drow + rr, n = colb + lr;
                    float pre = acc[rr] + P.xpre[(size_t)(tq * 128 + b) * 3072 + 2 * DH + n]
                              + P.b0[2 * DH + n];
                    float z = tanhf(pre);
                    float f = P.fg[(size_t)b * DH + n];
                    float hv = P.h[(size_t)b * DH + n];
                    float nh = (1.f - f) * hv + f * z;
                    P.h1[(size_t)b * DH + n] = nh;
                    P.h1b[(size_t)b * DH + n] = f2bf(nh);
                }
            }
        }
        grid.sync();

        // ---- Phase C: L2 f2,i2 (folded K=1024) and z x-part (h1 @ W1z[:1024]) ----
        for (int j = wg; j < 384; j += NWG) {
            int q = j >> 7, r = j & 127, mb = r >> 5, nb = r & 31;
            const unsigned short* wt; int wstr;
            if (q == 0)      { wt = P.Wff; wstr = DH; }
            else if (q == 1) { wt = P.Wii; wstr = DH; }
            else             { wt = P.W1z; wstr = DK2; }
            int wm = tile >> 1, wn = tile & 1;
            int rowb = mb * 32 + wm * 16, colb = nb * 32 + wn * 16;
            const unsigned short* ap = P.h1b + (size_t)(rowb + lr) * DH + ks * 512 + kb;
            const unsigned short* wp = wt + (size_t)(colb + lr) * wstr + ks * 512 + kb;
            f32x4 acc = mm16(ap, wp, 16);
            __syncthreads();
            if (ks == 1) {
                s_red[tile][drow + 0][lr] = acc[0]; s_red[tile][drow + 1][lr] = acc[1];
                s_red[tile][drow + 2][lr] = acc[2]; s_red[tile][drow + 3][lr] = acc[3];
            }
            __syncthreads();
            if (ks == 0) {
                acc[0] += s_red[tile][drow + 0][lr]; acc[1] += s_red[tile][drow + 1][lr];
                acc[2] += s_red[tile][drow + 2][lr]; acc[3] += s_red[tile][drow + 3][lr];
                #pragma unroll
                for (int rr = 0; rr < 4; ++rr) {
                    int b = rowb + drow + rr, n = colb + lr;
                    if (q == 0) {
                        float pre = acc[rr] + P.b1[n];
                        P.f2g[(size_t)b * DH + n] = 1.f / (1.f + __expf(-pre));
                    } else if (q == 1) {
                        float pre = acc[rr] + P.b1[DH + n];
                        float s = 1.f / (1.f + __expf(-pre));
                        P.h1i2b[(size_t)b * DH + n] = f2bf(P.h1[(size_t)b * DH + n] * s);
                    } else {
                        P.zx[(size_t)b * DH + n] = acc[rr] + P.b1[2 * DH + n];
                    }
                }
            }
        }
        grid.sync();

        // ---- Phase D: z2 = tanh(zx + (h1*i2) @ W1z[1024:]); h = (1-f2)h1 + f2 z2 ----
        if (wg < 128) {
            int mb = wg >> 5, nb = wg & 31;
            int wm = tile >> 1, wn = tile & 1;
            int rowb = mb * 32 + wm * 16, colb = nb * 32 + wn * 16;
            const unsigned short* ap = P.h1i2b + (size_t)(rowb + lr) * DH + ks * 512 + kb;
            const unsigned short* wp = P.W1z + (size_t)(colb + lr) * DK2 + 1024 + ks * 512 + kb;
            f32x4 acc = mm16(ap, wp, 16);
            __syncthreads();
            if (ks == 1) {
                s_red[tile][drow + 0][lr] = acc[0]; s_red[tile][drow + 1][lr] = acc[1];
                s_red[tile][drow + 2][lr] = acc[2]; s_red[tile][drow + 3][lr] = acc[3];
            }
            __syncthreads();
            if (ks == 0) {
                acc[0] += s_red[tile][drow + 0][lr]; acc[1] += s_red[tile][drow + 1][lr];
                acc[2] += s_red[tile][drow + 2][lr]; acc[3] += s_red[tile][drow + 3][lr];
                #pragma unroll
                for (int rr = 0; rr < 4; ++rr) {
                    int b = rowb + drow + rr, n = colb + lr;
                    float pre = P.zx[(size_t)b * DH + n] + acc[rr];
                    float z = tanhf(pre);
                    float f2 = P.f2g[(size_t)b * DH + n];
                    float h1v = P.h1[(size_t)b * DH + n];
                    float nh = (1.f - f2) * h1v + f2 * z;
                    P.h[(size_t)b * DH + n] = nh;
                    P.hb[(size_t)b * DH + n] = f2bf(nh);
                    if (t == TSEQ - 1) P.out[(size_t)b * DH + n] = nh;
                }
            }
        }
        grid.sync();
    }
}

extern "C" void kernel_launch(void* const* d_in, const int* in_sizes, int n_in,
                              void* d_out, int out_size, void* d_ws, size_t ws_size,
                              hipStream_t stream) {
    const float* x  = (const float*)d_in[0];
    const float* W0 = (const float*)d_in[1];
    const float* b0 = (const float*)d_in[2];
    const float* W1 = (const float*)d_in[3];
    const float* b1 = (const float*)d_in[4];

    char* ws = (char*)d_ws;
    size_t off = 0;
    auto alloc = [&](size_t bytes) { void* p = ws + off; off += (bytes + 255) & ~(size_t)255; return p; };

    unsigned short* W0f = (unsigned short*)alloc((size_t)DH * DK2 * 2);
    unsigned short* W0i = (unsigned short*)alloc((size_t)DH * DK2 * 2);
    unsigned short* W0z = (unsigned short*)alloc((size_t)DH * DK2 * 2);
    unsigned short* W1z = (unsigned short*)alloc((size_t)DH * DK2 * 2);
    unsigned short* Wff = (unsigned short*)alloc((size_t)DH * DH * 2);
    unsigned short* Wii = (unsigned short*)alloc((size_t)DH * DH * 2);
    float* xpre = (float*)alloc((size_t)32 * 128 * 3072 * 4);
    float* h    = (float*)alloc((size_t)BB * DH * 4);
    unsigned short* hb = (unsigned short*)alloc((size_t)BB * DH * 2);
    float* fg   = (float*)alloc((size_t)BB * DH * 4);
    unsigned short* hib = (unsigned short*)alloc((size_t)BB * DH * 2);
    float* h1   = (float*)alloc((size_t)BB * DH * 4);
    unsigned short* h1b = (unsigned short*)alloc((size_t)BB * DH * 2);
    float* f2g  = (float*)alloc((size_t)BB * DH * 4);
    unsigned short* h1i2b = (unsigned short*)alloc((size_t)BB * DH * 2);
    float* zx   = (float*)alloc((size_t)BB * DH * 4);
    (void)ws_size; (void)in_sizes; (void)n_in; (void)out_size;

    prep_weights<<<10240, 256, 0, stream>>>(W0, W1, W0f, W0i, W0z, Wff, Wii, W1z);

    GruParams p;
    p.x = x; p.b0 = b0; p.b1 = b1;
    p.W0f = W0f; p.W0i = W0i; p.W0z = W0z; p.Wff = Wff; p.Wii = Wii; p.W1z = W1z;
    p.xpre = xpre; p.h = h; p.hb = hb; p.fg = fg; p.hib = hib;
    p.h1 = h1; p.h1b = h1b; p.f2g = f2g; p.h1i2b = h1i2b; p.zx = zx;
    p.out = (float*)d_out;

    void* args[] = { &p };
    hipLaunchCooperativeKernel((const void*)gru_main, dim3(NWG), dim3(NTHR), args, 0, stream);
}

// Round 2
// 19231.441 us; speedup vs baseline: 2.2402x; 2.2402x over previous
//
#include <hip/hip_runtime.h>

#define BB    128     // batch
#define TSEQ  256     // time steps
#define DH    1024    // hidden
#define DK2   2048    // concat K
#define NWG   256
#define NTHR  512

typedef __attribute__((ext_vector_type(8))) short short8;
typedef __attribute__((ext_vector_type(4))) float f32x4;

__device__ __forceinline__ unsigned short f2bf(float f) {
    union { float f; unsigned int u; } v; v.f = f;
    unsigned int r = (v.u + 0x7FFFu + ((v.u >> 16) & 1u)) >> 16;  // RNE
    return (unsigned short)r;
}

// ---------------- lightweight grid barrier (agent-scope) ----------------
__device__ __forceinline__ void gbar(int* arrive, int* gen, int lg) {
    __syncthreads();                 // drains vmcnt for whole WG
    if (threadIdx.x == 0) {
        __builtin_amdgcn_fence(__ATOMIC_RELEASE, "agent");   // L2 writeback
        int prev = __hip_atomic_fetch_add(arrive, 1, __ATOMIC_RELAXED,
                                          __HIP_MEMORY_SCOPE_AGENT);
        if (prev == NWG - 1) {
            __hip_atomic_store(arrive, 0, __ATOMIC_RELAXED, __HIP_MEMORY_SCOPE_AGENT);
            __hip_atomic_store(gen, lg + 1, __ATOMIC_RELEASE, __HIP_MEMORY_SCOPE_AGENT);
        } else {
            while (__hip_atomic_load(gen, __ATOMIC_RELAXED,
                                     __HIP_MEMORY_SCOPE_AGENT) < lg + 1) {
                __builtin_amdgcn_s_sleep(1);
            }
        }
        __builtin_amdgcn_fence(__ATOMIC_ACQUIRE, "agent");   // L1/L2 invalidate
    }
    __syncthreads();
}

// ---------------- weight prep: transpose f32 [K][N] -> bf16 [N][K] (+fold for L2 f,i) ----------------
__global__ __launch_bounds__(256) void prep_weights(const float* __restrict__ W0,
                                                    const float* __restrict__ W1,
                                                    unsigned short* W0f, unsigned short* W0i,
                                                    unsigned short* W0z, unsigned short* Wff,
                                                    unsigned short* Wii, unsigned short* W1z,
                                                    int* barrier_state) {
    if (blockIdx.x == 0 && threadIdx.x == 0) { barrier_state[0] = 0; barrier_state[64] = 0; }
    __shared__ float tl[32][33];
    const int tx = threadIdx.x & 31, ty = threadIdx.x >> 5;  // ty 0..7
    int job = blockIdx.x;
    if (job < 6144) {                       // W0 gates: 3 x [2048 x 1024] transpose
        int g = job >> 11, r = job & 2047, kt = r >> 5, nt = r & 31;
        const float* src = W0 + (size_t)g * DK2 * DH;
        unsigned short* dst = (g == 0) ? W0f : ((g == 1) ? W0i : W0z);
        #pragma unroll
        for (int i = 0; i < 4; ++i)
            tl[ty + i * 8][tx] = src[(size_t)(kt * 32 + ty + i * 8) * DH + nt * 32 + tx];
        __syncthreads();
        #pragma unroll
        for (int i = 0; i < 4; ++i)
            dst[(size_t)(nt * 32 + ty + i * 8) * DK2 + kt * 32 + tx] = f2bf(tl[tx][ty + i * 8]);
    } else if (job < 8192) {                // W1 f,i folded: [1024][1024]
        int r = job - 6144; int g = r >> 10; r &= 1023;
        int kt = r >> 5, nt = r & 31;
        const float* src = W1 + (size_t)g * DK2 * DH;
        unsigned short* dst = (g == 0) ? Wff : Wii;
        #pragma unroll
        for (int i = 0; i < 4; ++i)
            tl[ty + i * 8][tx] = src[(size_t)(kt * 32 + ty + i * 8) * DH + nt * 32 + tx]
                               + src[(size_t)(1024 + kt * 32 + ty + i * 8) * DH + nt * 32 + tx];
        __syncthreads();
        #pragma unroll
        for (int i = 0; i < 4; ++i)
            dst[(size_t)(nt * 32 + ty + i * 8) * DH + kt * 32 + tx] = f2bf(tl[tx][ty + i * 8]);
    } else {                                // W1 z: [2048 x 1024] transpose
        int r = job - 8192; int kt = r >> 5, nt = r & 31;
        const float* src = W1 + (size_t)2 * DK2 * DH;
        #pragma unroll
        for (int i = 0; i < 4; ++i)
            tl[ty + i * 8][tx] = src[(size_t)(kt * 32 + ty + i * 8) * DH + nt * 32 + tx];
        __syncthreads();
        #pragma unroll
        for (int i = 0; i < 4; ++i)
            W1z[(size_t)(nt * 32 + ty + i * 8) * DK2 + kt * 32 + tx] = f2bf(tl[tx][ty + i * 8]);
    }
}

// ---------------- main persistent kernel ----------------
struct GruParams {
    const float* x;                 // [128][256][1024] f32
    const float* b0;                // [3][1024]
    const float* b1;                // [3][1024]
    const unsigned short* W0f;      // [1024 n][2048 k]  (k<1024: x-part, k>=1024: h-part)
    const unsigned short* W0i;
    const unsigned short* W0z;
    const unsigned short* Wff;      // [1024][1024] folded
    const unsigned short* Wii;
    const unsigned short* W1z;      // [1024 n][2048 k]  (k<1024: h1-part, k>=1024: h1*i2-part)
    float* xpre;                    // [32][128][3072] f32 chunk of x-part preacts
    float* h;  unsigned short* hb;  // h master f32 + bf16
    float* fg;                      // L1 f gate f32
    unsigned short* hib;            // h*i bf16
    float* h1;                      // h1 master f32
    unsigned short* hcat;           // [128][2048] bf16: [h1 | h1*i2]
    float* f2g;
    float* out;
    int* bar;                       // bar[0]=arrive, bar[64]=gen
};

template<int ITERS>
__device__ __forceinline__ f32x4 mmk(const unsigned short* __restrict__ ap,
                                     const unsigned short* __restrict__ wp) {
    f32x4 acc = {0.f, 0.f, 0.f, 0.f};
    #pragma unroll
    for (int k = 0; k < ITERS; ++k) {
        short8 a = *(const short8*)ap;
        short8 b = *(const short8*)wp;
        ap += 32; wp += 32;
        acc = __builtin_amdgcn_mfma_f32_16x16x32_bf16(a, b, acc, 0, 0, 0);
    }
    return acc;
}

__global__ __launch_bounds__(NTHR) void gru_main(GruParams P) {
    const int wg   = blockIdx.x;
    const int tid  = threadIdx.x;
    const int lane = tid & 63;
    const int wv   = tid >> 6;         // 0..7
    const int tile = wv & 3, ks2 = wv >> 2;   // 32x32 tiles: 4 sub-tiles x 2-way ksplit
    const int cw   = wv & 1, ks4 = wv >> 1;   // 16x32 tiles: 2 col-tiles x 4-way ksplit
    const int lr   = lane & 15;
    const int kb   = (lane >> 4) * 8;  // k-offset within frag
    const int drow = (lane >> 4) * 4;  // D-frag row base

    __shared__ float s_red[4][16][16];     // 32x32 phases (A, C)
    __shared__ float s_r2[2][3][16][16];   // 16x32 phases (B, D)

    int* arrive = P.bar;
    int* gen    = P.bar + 64;
    int lg = 0;

    // init h = 0
    for (int idx = wg * NTHR + tid; idx < BB * DH; idx += NWG * NTHR) {
        P.h[idx] = 0.f; P.hb[idx] = 0;
    }
    gbar(arrive, gen, lg); ++lg;

    for (int t = 0; t < TSEQ; ++t) {
        // ---- chunk GEMM every 32 steps: xpre[tt][b][g*1024+n] = x[b][t+tt] @ W0[g][:1024] ----
        if ((t & 31) == 0) {
            for (int j = wg; j < 1536; j += NWG) {
                int mb = j / 48, nj = j % 48;          // mb = tt, 64 cols per job
                int b = wv * 16 + lr;
                const float* xp = P.x + ((size_t)b * TSEQ + (t + mb)) * DH + kb;
                int cbase = nj * 64;
                int g = cbase >> 10, nb0 = cbase & 1023;
                const unsigned short* wt = (g == 0) ? P.W0f : ((g == 1) ? P.W0i : P.W0z);
                const unsigned short* wp = wt + (size_t)(nb0 + lr) * DK2 + kb;
                f32x4 a0 = {0,0,0,0}, a1 = a0, a2 = a0, a3 = a0;
                #pragma unroll 2
                for (int k = 0; k < DH; k += 32) {
                    f32x4 lo = *(const f32x4*)(xp + k);
                    f32x4 hi = *(const f32x4*)(xp + k + 4);
                    short8 av;
                    av[0] = (short)f2bf(lo[0]); av[1] = (short)f2bf(lo[1]);
                    av[2] = (short)f2bf(lo[2]); av[3] = (short)f2bf(lo[3]);
                    av[4] = (short)f2bf(hi[0]); av[5] = (short)f2bf(hi[1]);
                    av[6] = (short)f2bf(hi[2]); av[7] = (short)f2bf(hi[3]);
                    short8 b0v = *(const short8*)(wp + k);
                    short8 b1v = *(const short8*)(wp + (size_t)16 * DK2 + k);
                    short8 b2v = *(const short8*)(wp + (size_t)32 * DK2 + k);
                    short8 b3v = *(const short8*)(wp + (size_t)48 * DK2 + k);
                    a0 = __builtin_amdgcn_mfma_f32_16x16x32_bf16(av, b0v, a0, 0, 0, 0);
                    a1 = __builtin_amdgcn_mfma_f32_16x16x32_bf16(av, b1v, a1, 0, 0, 0);
                    a2 = __builtin_amdgcn_mfma_f32_16x16x32_bf16(av, b2v, a2, 0, 0, 0);
                    a3 = __builtin_amdgcn_mfma_f32_16x16x32_bf16(av, b3v, a3, 0, 0, 0);
                }
                int rowb = mb * 128 + wv * 16 + drow;
                #pragma unroll
                for (int cf = 0; cf < 4; ++cf) {
                    f32x4 acc = (cf == 0) ? a0 : ((cf == 1) ? a1 : ((cf == 2) ? a2 : a3));
                    int col = cbase + cf * 16 + lr;
                    #pragma unroll
                    for (int rr = 0; rr < 4; ++rr)
                        P.xpre[(size_t)(rowb + rr) * 3072 + col] = acc[rr];
                }
            }
            gbar(arrive, gen, lg); ++lg;
        }
        const int tq = t & 31;

        // ---- Phase A: L1 f,i = sigmoid(xpre + h @ W0{f,i}[h-part] + b0) ----
        {
            int g = wg >> 7, r = wg & 127, mb = r >> 5, nb = r & 31;
            const unsigned short* wt = g ? P.W0i : P.W0f;
            int wm = tile >> 1, wn = tile & 1;
            int rowb = mb * 32 + wm * 16, colb = nb * 32 + wn * 16;
            const unsigned short* ap = P.hb + (size_t)(rowb + lr) * DH + ks2 * 512 + kb;
            const unsigned short* wp = wt + (size_t)(colb + lr) * DK2 + 1024 + ks2 * 512 + kb;
            f32x4 acc = mmk<16>(ap, wp);
            if (ks2 == 1) {
                s_red[tile][drow + 0][lr] = acc[0]; s_red[tile][drow + 1][lr] = acc[1];
                s_red[tile][drow + 2][lr] = acc[2]; s_red[tile][drow + 3][lr] = acc[3];
            }
            __syncthreads();
            if (ks2 == 0) {
                acc[0] += s_red[tile][drow + 0][lr]; acc[1] += s_red[tile][drow + 1][lr];
                acc[2] += s_red[tile][drow + 2][lr]; acc[3] += s_red[tile][drow + 3][lr];
                #pragma unroll
                for (int rr = 0; rr < 4; ++rr) {
                    int b = rowb + drow + rr, n = colb + lr;
                    float pre = acc[rr] + P.xpre[(size_t)(tq * 128 + b) * 3072 + g * DH + n]
                              + P.b0[g * DH + n];
                    float s = 1.f / (1.f + __expf(-pre));
                    if (g == 0) P.fg[(size_t)b * DH + n] = s;
                    else        P.hib[(size_t)b * DH + n] = f2bf(P.h[(size_t)b * DH + n] * s);
                }
            }
        }
        gbar(arrive, gen, lg); ++lg;

        // ---- Phase B: L1 z = tanh(xpre_z + (h*i) @ W0z[h-part] + b0z); h1 = (1-f)h + f z ----
        {
            int mb = wg >> 5, nb = wg & 31;              // 16x32 tile
            int rowb = mb * 16, colb = nb * 32 + cw * 16;
            const unsigned short* ap = P.hib + (size_t)(rowb + lr) * DH + ks4 * 256 + kb;
            const unsigned short* wp = P.W0z + (size_t)(colb + lr) * DK2 + 1024 + ks4 * 256 + kb;
            f32x4 acc = mmk<8>(ap, wp);
            if (ks4 != 0) {
                s_r2[cw][ks4 - 1][drow + 0][lr] = acc[0]; s_r2[cw][ks4 - 1][drow + 1][lr] = acc[1];
                s_r2[cw][ks4 - 1][drow + 2][lr] = acc[2]; s_r2[cw][ks4 - 1][drow + 3][lr] = acc[3];
            }
            __syncthreads();
            if (ks4 == 0) {
                #pragma unroll
                for (int rr = 0; rr < 4; ++rr)
                    acc[rr] += s_r2[cw][0][drow + rr][lr] + s_r2[cw][1][drow + rr][lr]
                             + s_r2[cw][2][drow + rr][lr];
                #pragma unroll
                for (int rr = 0; rr < 4; ++rr) {
                    int b = rowb + drow + rr, n = colb + lr;
                    float pre = acc[rr] + P.xpre[(size_t)(tq * 128 + b) * 3072 + 2 * DH + n]
                              + P.b0[2 * DH + n];
                    float z = tanhf(pre);
                    float f = P.fg[(size_t)b * DH + n];
                    float hv = P.h[(size_t)b * DH + n];
                    float nh = (1.f - f) * hv + f * z;
                    P.h1[(size_t)b * DH + n] = nh;
                    P.hcat[(size_t)b * DK2 + n] = f2bf(nh);
                }
            }
        }
        gbar(arrive, gen, lg); ++lg;

        // ---- Phase C: L2 f2 = sigmoid(h1 @ Wff + b1f), i2 = sigmoid(h1 @ Wii + b1i) ----
        {
            int g = wg >> 7, r = wg & 127, mb = r >> 5, nb = r & 31;
            const unsigned short* wt = g ? P.Wii : P.Wff;
            int wm = tile >> 1, wn = tile & 1;
            int rowb = mb * 32 + wm * 16, colb = nb * 32 + wn * 16;
            const unsigned short* ap = P.hcat + (size_t)(rowb + lr) * DK2 + ks2 * 512 + kb;  // h1 part
            const unsigned short* wp = wt + (size_t)(colb + lr) * DH + ks2 * 512 + kb;
            f32x4 acc = mmk<16>(ap, wp);
            if (ks2 == 1) {
                s_red[tile][drow + 0][lr] = acc[0]; s_red[tile][drow + 1][lr] = acc[1];
                s_red[tile][drow + 2][lr] = acc[2]; s_red[tile][drow + 3][lr] = acc[3];
            }
            __syncthreads();
            if (ks2 == 0) {
                acc[0] += s_red[tile][drow + 0][lr]; acc[1] += s_red[tile][drow + 1][lr];
                acc[2] += s_red[tile][drow + 2][lr]; acc[3] += s_red[tile][drow + 3][lr];
                #pragma unroll
                for (int rr = 0; rr < 4; ++rr) {
                    int b = rowb + drow + rr, n = colb + lr;
                    float pre = acc[rr] + P.b1[g * DH + n];
                    float s = 1.f / (1.f + __expf(-pre));
                    if (g == 0) P.f2g[(size_t)b * DH + n] = s;
                    else        P.hcat[(size_t)b * DK2 + DH + n] = f2bf(P.h1[(size_t)b * DH + n] * s);
                }
            }
        }
        gbar(arrive, gen, lg); ++lg;

        // ---- Phase D: z2 = tanh([h1 | h1*i2] @ W1z + b1z); h = (1-f2)h1 + f2 z2 ----
        {
            int mb = wg >> 5, nb = wg & 31;              // 16x32 tile, K=2048
            int rowb = mb * 16, colb = nb * 32 + cw * 16;
            const unsigned short* ap = P.hcat + (size_t)(rowb + lr) * DK2 + ks4 * 512 + kb;
            const unsigned short* wp = P.W1z + (size_t)(colb + lr) * DK2 + ks4 * 512 + kb;
            f32x4 acc = mmk<16>(ap, wp);
            if (ks4 != 0) {
                s_r2[cw][ks4 - 1][drow + 0][lr] = acc[0]; s_r2[cw][ks4 - 1][drow + 1][lr] = acc[1];
                s_r2[cw][ks4 - 1][drow + 2][lr] = acc[2]; s_r2[cw][ks4 - 1][drow + 3][lr] = acc[3];
            }
            __syncthreads();
            if (ks4 == 0) {
                #pragma unroll
                for (int rr = 0; rr < 4; ++rr)
                    acc[rr] += s_r2[cw][0][drow + rr][lr] + s_r2[cw][1][drow + rr][lr]
                             + s_r2[cw][2][drow + rr][lr];
                #pragma unroll
                for (int rr = 0; rr < 4; ++rr) {
                    int b = rowb + drow + rr, n = colb + lr;
                    float pre = acc[rr] + P.b1[2 * DH + n];
                    float z = tanhf(pre);
                    float f2 = P.f2g[(size_t)b * DH + n];
                    float h1v = P.h1[(size_t)b * DH + n];
                    float nh = (1.f - f2) * h1v + f2 * z;
                    P.h[(size_t)b * DH + n] = nh;
                    P.hb[(size_t)b * DH + n] = f2bf(nh);
                    if (t == TSEQ - 1) P.out[(size_t)b * DH + n] = nh;
                }
            }
        }
        gbar(arrive, gen, lg); ++lg;
    }
}

extern "C" void kernel_launch(void* const* d_in, const int* in_sizes, int n_in,
                              void* d_out, int out_size, void* d_ws, size_t ws_size,
                              hipStream_t stream) {
    const float* x  = (const float*)d_in[0];
    const float* W0 = (const float*)d_in[1];
    const float* b0 = (const float*)d_in[2];
    const float* W1 = (const float*)d_in[3];
    const float* b1 = (const float*)d_in[4];

    char* ws = (char*)d_ws;
    size_t off = 0;
    auto alloc = [&](size_t bytes) { void* p = ws + off; off += (bytes + 255) & ~(size_t)255; return p; };

    unsigned short* W0f = (unsigned short*)alloc((size_t)DH * DK2 * 2);
    unsigned short* W0i = (unsigned short*)alloc((size_t)DH * DK2 * 2);
    unsigned short* W0z = (unsigned short*)alloc((size_t)DH * DK2 * 2);
    unsigned short* W1z = (unsigned short*)alloc((size_t)DH * DK2 * 2);
    unsigned short* Wff = (unsigned short*)alloc((size_t)DH * DH * 2);
    unsigned short* Wii = (unsigned short*)alloc((size_t)DH * DH * 2);
    float* xpre = (float*)alloc((size_t)32 * 128 * 3072 * 4);
    float* h    = (float*)alloc((size_t)BB * DH * 4);
    unsigned short* hb = (unsigned short*)alloc((size_t)BB * DH * 2);
    float* fg   = (float*)alloc((size_t)BB * DH * 4);
    unsigned short* hib = (unsigned short*)alloc((size_t)BB * DH * 2);
    float* h1   = (float*)alloc((size_t)BB * DH * 4);
    unsigned short* hcat = (unsigned short*)alloc((size_t)BB * DK2 * 2);
    float* f2g  = (float*)alloc((size_t)BB * DH * 4);
    int* bar    = (int*)alloc(1024);
    (void)ws_size; (void)in_sizes; (void)n_in; (void)out_size;

    prep_weights<<<10240, 256, 0, stream>>>(W0, W1, W0f, W0i, W0z, Wff, Wii, W1z, bar);

    GruParams p;
    p.x = x; p.b0 = b0; p.b1 = b1;
    p.W0f = W0f; p.W0i = W0i; p.W0z = W0z; p.Wff = Wff; p.Wii = Wii; p.W1z = W1z;
    p.xpre = xpre; p.h = h; p.hb = hb; p.fg = fg; p.hib = hib;
    p.h1 = h1; p.hcat = hcat; p.f2g = f2g;
    p.out = (float*)d_out;
    p.bar = bar;

    void* args[] = { &p };
    hipLaunchCooperativeKernel((const void*)gru_main, dim3(NWG), dim3(NTHR), args, 0, stream);
}

// Round 3
// 16142.055 us; speedup vs baseline: 2.6690x; 1.1914x over previous
//
#include <hip/hip_runtime.h>

#define BB    128     // batch
#define TSEQ  256     // time steps
#define DH    1024    // hidden
#define DK2   2048    // concat K
#define NWG   256
#define NTHR  512

typedef __attribute__((ext_vector_type(8))) short short8;
typedef __attribute__((ext_vector_type(4))) float f32x4;

__device__ __forceinline__ unsigned short f2bf(float f) {
    union { float f; unsigned int u; } v; v.f = f;
    unsigned int r = (v.u + 0x7FFFu + ((v.u >> 16) & 1u)) >> 16;  // RNE
    return (unsigned short)r;
}

// ---- coherent (device-scope) memory ops: bypass L1/L2 via sc0 sc1 ----
// write-through stores => visible at coherence point once vmcnt retires;
// loads force-miss L1/L2 => always read the coherence point. No cache-wide
// fences needed anywhere => weights stay L2-resident across all phases.
__device__ __forceinline__ void cstoref(float* p, float v) {
    asm volatile("global_store_dword %0, %1, off sc0 sc1" :: "v"(p), "v"(v) : "memory");
}
__device__ __forceinline__ void cstoreh(unsigned short* p, unsigned short v) {
    unsigned int w = v;
    asm volatile("global_store_short %0, %1, off sc0 sc1" :: "v"(p), "v"(w) : "memory");
}
#define CLOADF(dst, ptr) \
    asm volatile("global_load_dword %0, %1, off sc0 sc1" : "=v"(dst) : "v"(ptr))
#define CWAIT() do { asm volatile("s_waitcnt vmcnt(0)" ::: "memory"); \
                     __builtin_amdgcn_sched_barrier(0); } while (0)

// ---- hierarchical grid barrier: monotonic counters, no fences ----
// bar[0]=root cnt, bar[64]=root gen, bar[128+g*64]=group cnt, bar[640+g*64]=group gen
__device__ __forceinline__ void gbar(int* bar, int lg, int wg) {
    asm volatile("s_waitcnt vmcnt(0)" ::: "memory");   // drain coherent stores
    __syncthreads();
    if (threadIdx.x == 0) {
        const int g = wg & 7;
        int* gcnt = bar + 128 + g * 64;
        int* ggen = bar + 640 + g * 64;
        int prev = __hip_atomic_fetch_add(gcnt, 1, __ATOMIC_RELAXED, __HIP_MEMORY_SCOPE_AGENT);
        if (prev == lg * 32 + 31) {                    // last of group -> root
            int rp = __hip_atomic_fetch_add(bar, 1, __ATOMIC_RELAXED, __HIP_MEMORY_SCOPE_AGENT);
            if (rp == lg * 8 + 7) {
                __hip_atomic_store(bar + 64, lg + 1, __ATOMIC_RELAXED, __HIP_MEMORY_SCOPE_AGENT);
            } else {
                while (__hip_atomic_load(bar + 64, __ATOMIC_RELAXED, __HIP_MEMORY_SCOPE_AGENT) <= lg)
                    __builtin_amdgcn_s_sleep(1);
            }
            __hip_atomic_store(ggen, lg + 1, __ATOMIC_RELAXED, __HIP_MEMORY_SCOPE_AGENT);
        } else {
            while (__hip_atomic_load(ggen, __ATOMIC_RELAXED, __HIP_MEMORY_SCOPE_AGENT) <= lg)
                __builtin_amdgcn_s_sleep(1);
        }
    }
    __syncthreads();
}

// ---------------- weight prep + state init ----------------
__global__ __launch_bounds__(256) void prep_weights(const float* __restrict__ W0,
                                                    const float* __restrict__ W1,
                                                    unsigned short* W0f, unsigned short* W0i,
                                                    unsigned short* W0z, unsigned short* Wff,
                                                    unsigned short* Wii, unsigned short* W1z,
                                                    float* h, unsigned short* hb,
                                                    int* bar) {
    int job = blockIdx.x;
    if (job >= 10240) {                     // h, hb zero-init (64 blocks x 2048 elems)
        int i0 = (job - 10240) * 2048 + threadIdx.x;
        #pragma unroll
        for (int k = 0; k < 8; ++k) { int i = i0 + k * 256; h[i] = 0.f; hb[i] = 0; }
        return;
    }
    if (job == 0) {
        for (int i = threadIdx.x; i < 1280; i += 256) bar[i] = 0;
    }
    __shared__ float tl[32][33];
    const int tx = threadIdx.x & 31, ty = threadIdx.x >> 5;  // ty 0..7
    if (job < 6144) {                       // W0 gates: 3 x [2048 x 1024] transpose
        int g = job >> 11, r = job & 2047, kt = r >> 5, nt = r & 31;
        const float* src = W0 + (size_t)g * DK2 * DH;
        unsigned short* dst = (g == 0) ? W0f : ((g == 1) ? W0i : W0z);
        #pragma unroll
        for (int i = 0; i < 4; ++i)
            tl[ty + i * 8][tx] = src[(size_t)(kt * 32 + ty + i * 8) * DH + nt * 32 + tx];
        __syncthreads();
        #pragma unroll
        for (int i = 0; i < 4; ++i)
            dst[(size_t)(nt * 32 + ty + i * 8) * DK2 + kt * 32 + tx] = f2bf(tl[tx][ty + i * 8]);
    } else if (job < 8192) {                // W1 f,i folded: [1024][1024]
        int r = job - 6144; int g = r >> 10; r &= 1023;
        int kt = r >> 5, nt = r & 31;
        const float* src = W1 + (size_t)g * DK2 * DH;
        unsigned short* dst = (g == 0) ? Wff : Wii;
        #pragma unroll
        for (int i = 0; i < 4; ++i)
            tl[ty + i * 8][tx] = src[(size_t)(kt * 32 + ty + i * 8) * DH + nt * 32 + tx]
                               + src[(size_t)(1024 + kt * 32 + ty + i * 8) * DH + nt * 32 + tx];
        __syncthreads();
        #pragma unroll
        for (int i = 0; i < 4; ++i)
            dst[(size_t)(nt * 32 + ty + i * 8) * DH + kt * 32 + tx] = f2bf(tl[tx][ty + i * 8]);
    } else {                                // W1 z: [2048 x 1024] transpose
        int r = job - 8192; int kt = r >> 5, nt = r & 31;
        const float* src = W1 + (size_t)2 * DK2 * DH;
        #pragma unroll
        for (int i = 0; i < 4; ++i)
            tl[ty + i * 8][tx] = src[(size_t)(kt * 32 + ty + i * 8) * DH + nt * 32 + tx];
        __syncthreads();
        #pragma unroll
        for (int i = 0; i < 4; ++i)
            W1z[(size_t)(nt * 32 + ty + i * 8) * DK2 + kt * 32 + tx] = f2bf(tl[tx][ty + i * 8]);
    }
}

// ---------------- main persistent kernel ----------------
struct GruParams {
    const float* x;                 // [128][256][1024] f32 (read-only, cached)
    const float* b0;                // [3][1024] (read-only, cached)
    const float* b1;                // [3][1024]
    const unsigned short* W0f;      // [1024 n][2048 k] bf16 (read-only, cached: L2-resident)
    const unsigned short* W0i;
    const unsigned short* W0z;
    const unsigned short* Wff;      // [1024][1024] folded
    const unsigned short* Wii;
    const unsigned short* W1z;      // [1024 n][2048 k]
    float* xpre;                    // [32][128][3072] f32 (coherent)
    float* h;  unsigned short* hb;  // h master f32 + bf16 (coherent)
    float* fg;                      // (coherent)
    unsigned short* hib;            // (coherent)
    float* h1;                      // (coherent)
    unsigned short* hcat;           // [128][2048] bf16: [h1 | h1*i2] (coherent)
    float* f2g;                     // (coherent)
    float* out;
    int* bar;
};

// A-operand (activations) loaded coherently, issue-all-then-wait; weights via
// normal cached loads (L2 hits after warmup), scheduled freely by compiler.
template<int ITERS>
__device__ __forceinline__ f32x4 mmk_c(const unsigned short* __restrict__ ap,
                                       const unsigned short* __restrict__ wp) {
    short8 a[ITERS];
    short8 bw[ITERS];
    #pragma unroll
    for (int k = 0; k < ITERS; ++k)
        asm volatile("global_load_dwordx4 %0, %1, off sc0 sc1"
                     : "=v"(a[k]) : "v"(ap + (size_t)k * 32));
    #pragma unroll
    for (int k = 0; k < ITERS; ++k)
        bw[k] = *(const short8*)(wp + (size_t)k * 32);
    asm volatile("s_waitcnt vmcnt(0)" ::: "memory");
    __builtin_amdgcn_sched_barrier(0);
    f32x4 acc = {0.f, 0.f, 0.f, 0.f};
    #pragma unroll
    for (int k = 0; k < ITERS; ++k)
        acc = __builtin_amdgcn_mfma_f32_16x16x32_bf16(a[k], bw[k], acc, 0, 0, 0);
    return acc;
}

__global__ __launch_bounds__(NTHR) void gru_main(GruParams P) {
    const int wg   = blockIdx.x;
    const int tid  = threadIdx.x;
    const int lane = tid & 63;
    const int wv   = tid >> 6;         // 0..7
    const int tile = wv & 3, ks2 = wv >> 2;   // 32x32 tiles: 4 sub-tiles x 2-way ksplit
    const int cw   = wv & 1, ks4 = wv >> 1;   // 16x32 tiles: 2 col-tiles x 4-way ksplit
    const int lr   = lane & 15;
    const int kb   = (lane >> 4) * 8;  // k-offset within frag
    const int drow = (lane >> 4) * 4;  // D-frag row base

    __shared__ float s_red[4][16][16];     // 32x32 phases (A, C)
    __shared__ float s_r2[2][3][16][16];   // 16x32 phases (B, D)

    int lg = 0;

    for (int t = 0; t < TSEQ; ++t) {
        // ---- chunk GEMM every 32 steps: xpre[tt][b][g*1024+n] = x[b][t+tt] @ W0[g][:1024] ----
        if ((t & 31) == 0) {
            for (int j = wg; j < 1536; j += NWG) {
                int mb = j / 48, nj = j % 48;          // mb = tt, 64 cols per job
                int b = wv * 16 + lr;
                const float* xp = P.x + ((size_t)b * TSEQ + (t + mb)) * DH + kb;
                int cbase = nj * 64;
                int g = cbase >> 10, nb0 = cbase & 1023;
                const unsigned short* wt = (g == 0) ? P.W0f : ((g == 1) ? P.W0i : P.W0z);
                const unsigned short* wp = wt + (size_t)(nb0 + lr) * DK2 + kb;
                f32x4 a0 = {0,0,0,0}, a1 = a0, a2 = a0, a3 = a0;
                #pragma unroll 2
                for (int k = 0; k < DH; k += 32) {
                    f32x4 lo = *(const f32x4*)(xp + k);
                    f32x4 hi = *(const f32x4*)(xp + k + 4);
                    short8 av;
                    av[0] = (short)f2bf(lo[0]); av[1] = (short)f2bf(lo[1]);
                    av[2] = (short)f2bf(lo[2]); av[3] = (short)f2bf(lo[3]);
                    av[4] = (short)f2bf(hi[0]); av[5] = (short)f2bf(hi[1]);
                    av[6] = (short)f2bf(hi[2]); av[7] = (short)f2bf(hi[3]);
                    short8 b0v = *(const short8*)(wp + k);
                    short8 b1v = *(const short8*)(wp + (size_t)16 * DK2 + k);
                    short8 b2v = *(const short8*)(wp + (size_t)32 * DK2 + k);
                    short8 b3v = *(const short8*)(wp + (size_t)48 * DK2 + k);
                    a0 = __builtin_amdgcn_mfma_f32_16x16x32_bf16(av, b0v, a0, 0, 0, 0);
                    a1 = __builtin_amdgcn_mfma_f32_16x16x32_bf16(av, b1v, a1, 0, 0, 0);
                    a2 = __builtin_amdgcn_mfma_f32_16x16x32_bf16(av, b2v, a2, 0, 0, 0);
                    a3 = __builtin_amdgcn_mfma_f32_16x16x32_bf16(av, b3v, a3, 0, 0, 0);
                }
                int rowb = mb * 128 + wv * 16 + drow;
                #pragma unroll
                for (int cf = 0; cf < 4; ++cf) {
                    f32x4 acc = (cf == 0) ? a0 : ((cf == 1) ? a1 : ((cf == 2) ? a2 : a3));
                    int col = cbase + cf * 16 + lr;
                    #pragma unroll
                    for (int rr = 0; rr < 4; ++rr)
                        cstoref(P.xpre + (size_t)(rowb + rr) * 3072 + col, acc[rr]);
                }
            }
            gbar(P.bar, lg, wg); ++lg;
        }
        const int tq = t & 31;

        // ---- Phase A: L1 f,i = sigmoid(xpre + h @ W0{f,i}[h-part] + b0) ----
        {
            int g = wg >> 7, r = wg & 127, mb = r >> 5, nb = r & 31;
            const unsigned short* wt = g ? P.W0i : P.W0f;
            int wm = tile >> 1, wn = tile & 1;
            int rowb = mb * 32 + wm * 16, colb = nb * 32 + wn * 16;
            const unsigned short* ap = P.hb + (size_t)(rowb + lr) * DH + ks2 * 512 + kb;
            const unsigned short* wp = wt + (size_t)(colb + lr) * DK2 + 1024 + ks2 * 512 + kb;
            f32x4 acc = mmk_c<16>(ap, wp);
            if (ks2 == 1) {
                s_red[tile][drow + 0][lr] = acc[0]; s_red[tile][drow + 1][lr] = acc[1];
                s_red[tile][drow + 2][lr] = acc[2]; s_red[tile][drow + 3][lr] = acc[3];
            }
            __syncthreads();
            if (ks2 == 0) {
                acc[0] += s_red[tile][drow + 0][lr]; acc[1] += s_red[tile][drow + 1][lr];
                acc[2] += s_red[tile][drow + 2][lr]; acc[3] += s_red[tile][drow + 3][lr];
                int n = colb + lr;
                float xv[4], hv[4] = {0.f, 0.f, 0.f, 0.f};
                #pragma unroll
                for (int rr = 0; rr < 4; ++rr) {
                    int b = rowb + drow + rr;
                    CLOADF(xv[rr], P.xpre + (size_t)(tq * 128 + b) * 3072 + g * DH + n);
                }
                if (g == 1) {
                    #pragma unroll
                    for (int rr = 0; rr < 4; ++rr)
                        CLOADF(hv[rr], P.h + (size_t)(rowb + drow + rr) * DH + n);
                }
                CWAIT();
                float bias = P.b0[g * DH + n];
                #pragma unroll
                for (int rr = 0; rr < 4; ++rr) {
                    int b = rowb + drow + rr;
                    float pre = acc[rr] + xv[rr] + bias;
                    float s = 1.f / (1.f + __expf(-pre));
                    if (g == 0) cstoref(P.fg + (size_t)b * DH + n, s);
                    else        cstoreh(P.hib + (size_t)b * DH + n, f2bf(hv[rr] * s));
                }
            }
        }
        gbar(P.bar, lg, wg); ++lg;

        // ---- Phase B: L1 z = tanh(xpre_z + (h*i) @ W0z[h-part] + b0z); h1 = (1-f)h + f z ----
        {
            int mb = wg >> 5, nb = wg & 31;              // 16x32 tile
            int rowb = mb * 16, colb = nb * 32 + cw * 16;
            const unsigned short* ap = P.hib + (size_t)(rowb + lr) * DH + ks4 * 256 + kb;
            const unsigned short* wp = P.W0z + (size_t)(colb + lr) * DK2 + 1024 + ks4 * 256 + kb;
            f32x4 acc = mmk_c<8>(ap, wp);
            if (ks4 != 0) {
                s_r2[cw][ks4 - 1][drow + 0][lr] = acc[0]; s_r2[cw][ks4 - 1][drow + 1][lr] = acc[1];
                s_r2[cw][ks4 - 1][drow + 2][lr] = acc[2]; s_r2[cw][ks4 - 1][drow + 3][lr] = acc[3];
            }
            __syncthreads();
            if (ks4 == 0) {
                #pragma unroll
                for (int rr = 0; rr < 4; ++rr)
                    acc[rr] += s_r2[cw][0][drow + rr][lr] + s_r2[cw][1][drow + rr][lr]
                             + s_r2[cw][2][drow + rr][lr];
                int n = colb + lr;
                float xv[4], fv[4], hv[4];
                #pragma unroll
                for (int rr = 0; rr < 4; ++rr) {
                    int b = rowb + drow + rr;
                    CLOADF(xv[rr], P.xpre + (size_t)(tq * 128 + b) * 3072 + 2 * DH + n);
                    CLOADF(fv[rr], P.fg + (size_t)b * DH + n);
                    CLOADF(hv[rr], P.h + (size_t)b * DH + n);
                }
                CWAIT();
                float bias = P.b0[2 * DH + n];
                #pragma unroll
                for (int rr = 0; rr < 4; ++rr) {
                    int b = rowb + drow + rr;
                    float pre = acc[rr] + xv[rr] + bias;
                    float z = tanhf(pre);
                    float nh = (1.f - fv[rr]) * hv[rr] + fv[rr] * z;
                    cstoref(P.h1 + (size_t)b * DH + n, nh);
                    cstoreh(P.hcat + (size_t)b * DK2 + n, f2bf(nh));
                }
            }
        }
        gbar(P.bar, lg, wg); ++lg;

        // ---- Phase C: L2 f2 = sigmoid(h1 @ Wff + b1f), i2 = sigmoid(h1 @ Wii + b1i) ----
        {
            int g = wg >> 7, r = wg & 127, mb = r >> 5, nb = r & 31;
            const unsigned short* wt = g ? P.Wii : P.Wff;
            int wm = tile >> 1, wn = tile & 1;
            int rowb = mb * 32 + wm * 16, colb = nb * 32 + wn * 16;
            const unsigned short* ap = P.hcat + (size_t)(rowb + lr) * DK2 + ks2 * 512 + kb;
            const unsigned short* wp = wt + (size_t)(colb + lr) * DH + ks2 * 512 + kb;
            f32x4 acc = mmk_c<16>(ap, wp);
            if (ks2 == 1) {
                s_red[tile][drow + 0][lr] = acc[0]; s_red[tile][drow + 1][lr] = acc[1];
                s_red[tile][drow + 2][lr] = acc[2]; s_red[tile][drow + 3][lr] = acc[3];
            }
            __syncthreads();
            if (ks2 == 0) {
                acc[0] += s_red[tile][drow + 0][lr]; acc[1] += s_red[tile][drow + 1][lr];
                acc[2] += s_red[tile][drow + 2][lr]; acc[3] += s_red[tile][drow + 3][lr];
                int n = colb + lr;
                float h1v[4] = {0.f, 0.f, 0.f, 0.f};
                if (g == 1) {
                    #pragma unroll
                    for (int rr = 0; rr < 4; ++rr)
                        CLOADF(h1v[rr], P.h1 + (size_t)(rowb + drow + rr) * DH + n);
                }
                CWAIT();
                float bias = P.b1[g * DH + n];
                #pragma unroll
                for (int rr = 0; rr < 4; ++rr) {
                    int b = rowb + drow + rr;
                    float pre = acc[rr] + bias;
                    float s = 1.f / (1.f + __expf(-pre));
                    if (g == 0) cstoref(P.f2g + (size_t)b * DH + n, s);
                    else        cstoreh(P.hcat + (size_t)b * DK2 + DH + n, f2bf(h1v[rr] * s));
                }
            }
        }
        gbar(P.bar, lg, wg); ++lg;

        // ---- Phase D: z2 = tanh([h1 | h1*i2] @ W1z + b1z); h = (1-f2)h1 + f2 z2 ----
        {
            int mb = wg >> 5, nb = wg & 31;              // 16x32 tile, K=2048
            int rowb = mb * 16, colb = nb * 32 + cw * 16;
            const unsigned short* ap = P.hcat + (size_t)(rowb + lr) * DK2 + ks4 * 512 + kb;
            const unsigned short* wp = P.W1z + (size_t)(colb + lr) * DK2 + ks4 * 512 + kb;
            f32x4 acc = mmk_c<16>(ap, wp);
            if (ks4 != 0) {
                s_r2[cw][ks4 - 1][drow + 0][lr] = acc[0]; s_r2[cw][ks4 - 1][drow + 1][lr] = acc[1];
                s_r2[cw][ks4 - 1][drow + 2][lr] = acc[2]; s_r2[cw][ks4 - 1][drow + 3][lr] = acc[3];
            }
            __syncthreads();
            if (ks4 == 0) {
                #pragma unroll
                for (int rr = 0; rr < 4; ++rr)
                    acc[rr] += s_r2[cw][0][drow + rr][lr] + s_r2[cw][1][drow + rr][lr]
                             + s_r2[cw][2][drow + rr][lr];
                int n = colb + lr;
                float f2v[4], h1v[4];
                #pragma unroll
                for (int rr = 0; rr < 4; ++rr) {
                    int b = rowb + drow + rr;
                    CLOADF(f2v[rr], P.f2g + (size_t)b * DH + n);
                    CLOADF(h1v[rr], P.h1 + (size_t)b * DH + n);
                }
                CWAIT();
                float bias = P.b1[2 * DH + n];
                #pragma unroll
                for (int rr = 0; rr < 4; ++rr) {
                    int b = rowb + drow + rr;
                    float pre = acc[rr] + bias;
                    float z = tanhf(pre);
                    float nh = (1.f - f2v[rr]) * h1v[rr] + f2v[rr] * z;
                    cstoref(P.h + (size_t)b * DH + n, nh);
                    cstoreh(P.hb + (size_t)b * DH + n, f2bf(nh));
                    if (t == TSEQ - 1) P.out[(size_t)b * DH + n] = nh;  // normal store: kernel-end flush
                }
            }
        }
        gbar(P.bar, lg, wg); ++lg;
    }
}

extern "C" void kernel_launch(void* const* d_in, const int* in_sizes, int n_in,
                              void* d_out, int out_size, void* d_ws, size_t ws_size,
                              hipStream_t stream) {
    const float* x  = (const float*)d_in[0];
    const float* W0 = (const float*)d_in[1];
    const float* b0 = (const float*)d_in[2];
    const float* W1 = (const float*)d_in[3];
    const float* b1 = (const float*)d_in[4];

    char* ws = (char*)d_ws;
    size_t off = 0;
    auto alloc = [&](size_t bytes) { void* p = ws + off; off += (bytes + 255) & ~(size_t)255; return p; };

    unsigned short* W0f = (unsigned short*)alloc((size_t)DH * DK2 * 2);
    unsigned short* W0i = (unsigned short*)alloc((size_t)DH * DK2 * 2);
    unsigned short* W0z = (unsigned short*)alloc((size_t)DH * DK2 * 2);
    unsigned short* W1z = (unsigned short*)alloc((size_t)DH * DK2 * 2);
    unsigned short* Wff = (unsigned short*)alloc((size_t)DH * DH * 2);
    unsigned short* Wii = (unsigned short*)alloc((size_t)DH * DH * 2);
    float* xpre = (float*)alloc((size_t)32 * 128 * 3072 * 4);
    float* h    = (float*)alloc((size_t)BB * DH * 4);
    unsigned short* hb = (unsigned short*)alloc((size_t)BB * DH * 2);
    float* fg   = (float*)alloc((size_t)BB * DH * 4);
    unsigned short* hib = (unsigned short*)alloc((size_t)BB * DH * 2);
    float* h1   = (float*)alloc((size_t)BB * DH * 4);
    unsigned short* hcat = (unsigned short*)alloc((size_t)BB * DK2 * 2);
    float* f2g  = (float*)alloc((size_t)BB * DH * 4);
    int* bar    = (int*)alloc(8192);
    (void)ws_size; (void)in_sizes; (void)n_in; (void)out_size;

    prep_weights<<<10304, 256, 0, stream>>>(W0, W1, W0f, W0i, W0z, Wff, Wii, W1z,
                                            h, hb, bar);

    GruParams p;
    p.x = x; p.b0 = b0; p.b1 = b1;
    p.W0f = W0f; p.W0i = W0i; p.W0z = W0z; p.Wff = Wff; p.Wii = Wii; p.W1z = W1z;
    p.xpre = xpre; p.h = h; p.hb = hb; p.fg = fg; p.hib = hib;
    p.h1 = h1; p.hcat = hcat; p.f2g = f2g;
    p.out = (float*)d_out;
    p.bar = bar;

    void* args[] = { &p };
    hipLaunchCooperativeKernel((const void*)gru_main, dim3(NWG), dim3(NTHR), args, 0, stream);
}

// Round 4
// 15871.919 us; speedup vs baseline: 2.7144x; 1.0170x over previous
//
#include <hip/hip_runtime.h>

#define BB    128     // batch
#define TSEQ  256     // time steps
#define DH    1024    // hidden
#define DK2   2048    // concat K
#define NWG   256
#define NTHR  512

typedef __attribute__((ext_vector_type(8))) short short8;
typedef __attribute__((ext_vector_type(4))) float f32x4;

__device__ __forceinline__ unsigned short f2bf(float f) {
    union { float f; unsigned int u; } v; v.f = f;
    unsigned int r = (v.u + 0x7FFFu + ((v.u >> 16) & 1u)) >> 16;  // RNE
    return (unsigned short)r;
}

// ---- coherent (device-scope) memory ops: bypass L1/L2 via sc0 sc1 ----
// write-through stores => visible at coherence point once vmcnt retires;
// loads force-miss L1/L2 => always read the coherence point. No cache-wide
// fences needed anywhere => weights stay L2-resident across all phases.
__device__ __forceinline__ void cstoref(float* p, float v) {
    asm volatile("global_store_dword %0, %1, off sc0 sc1" :: "v"(p), "v"(v) : "memory");
}
__device__ __forceinline__ void cstoreh(unsigned short* p, unsigned short v) {
    unsigned int w = v;
    asm volatile("global_store_short %0, %1, off sc0 sc1" :: "v"(p), "v"(w) : "memory");
}
#define CLOADF(dst, ptr) \
    asm volatile("global_load_dword %0, %1, off sc0 sc1" : "=v"(dst) : "v"(ptr))
#define CWAIT() do { asm volatile("s_waitcnt vmcnt(0)" ::: "memory"); \
                     __builtin_amdgcn_sched_barrier(0); } while (0)

// ---- hierarchical grid barrier: monotonic counters, no fences ----
// bar[0]=root cnt, bar[64]=root gen, bar[128+g*64]=group cnt, bar[640+g*64]=group gen
__device__ __forceinline__ void gbar(int* bar, int lg, int wg) {
    asm volatile("s_waitcnt vmcnt(0)" ::: "memory");   // drain coherent stores
    __syncthreads();
    if (threadIdx.x == 0) {
        const int g = wg & 7;
        int* gcnt = bar + 128 + g * 64;
        int* ggen = bar + 640 + g * 64;
        int prev = __hip_atomic_fetch_add(gcnt, 1, __ATOMIC_RELAXED, __HIP_MEMORY_SCOPE_AGENT);
        if (prev == lg * 32 + 31) {                    // last of group -> root
            int rp = __hip_atomic_fetch_add(bar, 1, __ATOMIC_RELAXED, __HIP_MEMORY_SCOPE_AGENT);
            if (rp == lg * 8 + 7) {
                __hip_atomic_store(bar + 64, lg + 1, __ATOMIC_RELAXED, __HIP_MEMORY_SCOPE_AGENT);
            } else {
                while (__hip_atomic_load(bar + 64, __ATOMIC_RELAXED, __HIP_MEMORY_SCOPE_AGENT) <= lg)
                    __builtin_amdgcn_s_sleep(1);
            }
            __hip_atomic_store(ggen, lg + 1, __ATOMIC_RELAXED, __HIP_MEMORY_SCOPE_AGENT);
        } else {
            while (__hip_atomic_load(ggen, __ATOMIC_RELAXED, __HIP_MEMORY_SCOPE_AGENT) <= lg)
                __builtin_amdgcn_s_sleep(1);
        }
    }
    __syncthreads();
}

// ---------------- weight prep + state init ----------------
__global__ __launch_bounds__(256) void prep_weights(const float* __restrict__ W0,
                                                    const float* __restrict__ W1,
                                                    unsigned short* W0f, unsigned short* W0i,
                                                    unsigned short* W0z, unsigned short* Wff,
                                                    unsigned short* Wii, unsigned short* W1z,
                                                    float* h, unsigned short* hb,
                                                    int* bar) {
    int job = blockIdx.x;
    if (job >= 10240) {                     // h, hb zero-init (64 blocks x 2048 elems)
        int i0 = (job - 10240) * 2048 + threadIdx.x;
        #pragma unroll
        for (int k = 0; k < 8; ++k) { int i = i0 + k * 256; h[i] = 0.f; hb[i] = 0; }
        return;
    }
    if (job == 0) {
        for (int i = threadIdx.x; i < 1280; i += 256) bar[i] = 0;
    }
    __shared__ float tl[32][33];
    const int tx = threadIdx.x & 31, ty = threadIdx.x >> 5;  // ty 0..7
    if (job < 6144) {                       // W0 gates: 3 x [2048 x 1024] transpose
        int g = job >> 11, r = job & 2047, kt = r >> 5, nt = r & 31;
        const float* src = W0 + (size_t)g * DK2 * DH;
        unsigned short* dst = (g == 0) ? W0f : ((g == 1) ? W0i : W0z);
        #pragma unroll
        for (int i = 0; i < 4; ++i)
            tl[ty + i * 8][tx] = src[(size_t)(kt * 32 + ty + i * 8) * DH + nt * 32 + tx];
        __syncthreads();
        #pragma unroll
        for (int i = 0; i < 4; ++i)
            dst[(size_t)(nt * 32 + ty + i * 8) * DK2 + kt * 32 + tx] = f2bf(tl[tx][ty + i * 8]);
    } else if (job < 8192) {                // W1 f,i folded: [1024][1024]
        int r = job - 6144; int g = r >> 10; r &= 1023;
        int kt = r >> 5, nt = r & 31;
        const float* src = W1 + (size_t)g * DK2 * DH;
        unsigned short* dst = (g == 0) ? Wff : Wii;
        #pragma unroll
        for (int i = 0; i < 4; ++i)
            tl[ty + i * 8][tx] = src[(size_t)(kt * 32 + ty + i * 8) * DH + nt * 32 + tx]
                               + src[(size_t)(1024 + kt * 32 + ty + i * 8) * DH + nt * 32 + tx];
        __syncthreads();
        #pragma unroll
        for (int i = 0; i < 4; ++i)
            dst[(size_t)(nt * 32 + ty + i * 8) * DH + kt * 32 + tx] = f2bf(tl[tx][ty + i * 8]);
    } else {                                // W1 z: [2048 x 1024] transpose
        int r = job - 8192; int kt = r >> 5, nt = r & 31;
        const float* src = W1 + (size_t)2 * DK2 * DH;
        #pragma unroll
        for (int i = 0; i < 4; ++i)
            tl[ty + i * 8][tx] = src[(size_t)(kt * 32 + ty + i * 8) * DH + nt * 32 + tx];
        __syncthreads();
        #pragma unroll
        for (int i = 0; i < 4; ++i)
            W1z[(size_t)(nt * 32 + ty + i * 8) * DK2 + kt * 32 + tx] = f2bf(tl[tx][ty + i * 8]);
    }
}

// ---------------- main persistent kernel ----------------
struct GruParams {
    const float* x;                 // [128][256][1024] f32 (read-only, cached)
    const float* b0;                // [3][1024] (read-only, cached)
    const float* b1;                // [3][1024]
    const unsigned short* W0f;      // [1024 n][2048 k] bf16 (read-only; n-band per XCD -> L2-resident)
    const unsigned short* W0i;
    const unsigned short* W0z;
    const unsigned short* Wff;      // [1024][1024] folded
    const unsigned short* Wii;
    const unsigned short* W1z;      // [1024 n][2048 k]
    float* xpre;                    // [32][128][3072] f32 (coherent)
    float* h;  unsigned short* hb;  // h master f32 + bf16 (coherent)
    float* fg;                      // (coherent)
    unsigned short* hib;            // (coherent)
    float* h1;                      // (coherent)
    unsigned short* hcat;           // [128][2048] bf16: [h1 | h1*i2] (coherent)
    float* f2g;                     // (coherent)
    float* out;
    int* bar;
};

// A-operand (activations) loaded coherently, issue-all-then-wait; weights via
// normal cached loads (L2-resident after step 1 thanks to XCD banding).
template<int ITERS>
__device__ __forceinline__ f32x4 mmk_c(const unsigned short* __restrict__ ap,
                                       const unsigned short* __restrict__ wp) {
    short8 a[ITERS];
    short8 bw[ITERS];
    #pragma unroll
    for (int k = 0; k < ITERS; ++k)
        asm volatile("global_load_dwordx4 %0, %1, off sc0 sc1"
                     : "=v"(a[k]) : "v"(ap + (size_t)k * 32));
    #pragma unroll
    for (int k = 0; k < ITERS; ++k)
        bw[k] = *(const short8*)(wp + (size_t)k * 32);
    asm volatile("s_waitcnt vmcnt(0)" ::: "memory");
    __builtin_amdgcn_sched_barrier(0);
    f32x4 acc = {0.f, 0.f, 0.f, 0.f};
    #pragma unroll
    for (int k = 0; k < ITERS; ++k)
        acc = __builtin_amdgcn_mfma_f32_16x16x32_bf16(a[k], bw[k], acc, 0, 0, 0);
    return acc;
}

__global__ __launch_bounds__(NTHR) void gru_main(GruParams P) {
    const int wg   = blockIdx.x;
    const int xcd  = wg & 7;           // measured round-robin WG->XCD [m09]; perf-only assumption
    const int sub  = wg >> 3;          // 0..31 within XCD
    const int tid  = threadIdx.x;
    const int lane = tid & 63;
    const int wv   = tid >> 6;         // 0..7
    const int tile = wv & 3, ks2 = wv >> 2;   // 32x32 tiles: 4 sub-tiles x 2-way ksplit
    const int cw   = wv & 1, ks4 = wv >> 1;   // 16x32 tiles: 2 col-tiles x 4-way ksplit
    const int lr   = lane & 15;
    const int kb   = (lane >> 4) * 8;  // k-offset within frag
    const int drow = (lane >> 4) * 4;  // D-frag row base

    __shared__ float s_red[4][16][16];     // 32x32 phases (A, C)
    __shared__ float s_r2[2][3][16][16];   // 16x32 phases (B, D)

    int lg = 0;

    // XCD column band: this WG only ever touches weight columns [xcd*128, xcd*128+128)
    const int band = xcd * 128;

    for (int t = 0; t < TSEQ; ++t) {
        // ---- chunk GEMM every 32 steps (XCD-banded): xpre[tt][b][g*1024+n], n in band ----
        if ((t & 31) == 0) {
            for (int j = sub; j < 192; j += 32) {
                int mb = j / 6, cj = j % 6;            // mb = tt, cj = col-job (3 gates x 2 halves)
                int g = cj >> 1, off = (cj & 1) * 64;
                int col0 = band + off;                 // within gate panel [0,1024)
                int b = wv * 16 + lr;
                const float* xp = P.x + ((size_t)b * TSEQ + (t + mb)) * DH + kb;
                const unsigned short* wt = (g == 0) ? P.W0f : ((g == 1) ? P.W0i : P.W0z);
                const unsigned short* wp = wt + (size_t)(col0 + lr) * DK2 + kb;
                f32x4 a0 = {0,0,0,0}, a1 = a0, a2 = a0, a3 = a0;
                #pragma unroll 2
                for (int k = 0; k < DH; k += 32) {
                    f32x4 lo = *(const f32x4*)(xp + k);
                    f32x4 hi = *(const f32x4*)(xp + k + 4);
                    short8 av;
                    av[0] = (short)f2bf(lo[0]); av[1] = (short)f2bf(lo[1]);
                    av[2] = (short)f2bf(lo[2]); av[3] = (short)f2bf(lo[3]);
                    av[4] = (short)f2bf(hi[0]); av[5] = (short)f2bf(hi[1]);
                    av[6] = (short)f2bf(hi[2]); av[7] = (short)f2bf(hi[3]);
                    short8 b0v = *(const short8*)(wp + k);
                    short8 b1v = *(const short8*)(wp + (size_t)16 * DK2 + k);
                    short8 b2v = *(const short8*)(wp + (size_t)32 * DK2 + k);
                    short8 b3v = *(const short8*)(wp + (size_t)48 * DK2 + k);
                    a0 = __builtin_amdgcn_mfma_f32_16x16x32_bf16(av, b0v, a0, 0, 0, 0);
                    a1 = __builtin_amdgcn_mfma_f32_16x16x32_bf16(av, b1v, a1, 0, 0, 0);
                    a2 = __builtin_amdgcn_mfma_f32_16x16x32_bf16(av, b2v, a2, 0, 0, 0);
                    a3 = __builtin_amdgcn_mfma_f32_16x16x32_bf16(av, b3v, a3, 0, 0, 0);
                }
                int rowb = mb * 128 + wv * 16 + drow;
                #pragma unroll
                for (int cf = 0; cf < 4; ++cf) {
                    f32x4 acc = (cf == 0) ? a0 : ((cf == 1) ? a1 : ((cf == 2) ? a2 : a3));
                    int col = g * DH + col0 + cf * 16 + lr;
                    #pragma unroll
                    for (int rr = 0; rr < 4; ++rr)
                        cstoref(P.xpre + (size_t)(rowb + rr) * 3072 + col, acc[rr]);
                }
            }
            gbar(P.bar, lg, wg); ++lg;
        }
        const int tq = t & 31;

        // ---- Phase A: L1 f,i = sigmoid(xpre + h @ W0{f,i}[h-part] + b0) ----
        {
            int gate = sub >> 4, rem = sub & 15;       // 2 gates x 16 tiles per XCD
            int mb = rem >> 2, nbq = rem & 3;
            const unsigned short* wt = gate ? P.W0i : P.W0f;
            int wm = tile >> 1, wn = tile & 1;
            int rowb = mb * 32 + wm * 16, colb = band + nbq * 32 + wn * 16;
            const unsigned short* ap = P.hb + (size_t)(rowb + lr) * DH + ks2 * 512 + kb;
            const unsigned short* wp = wt + (size_t)(colb + lr) * DK2 + 1024 + ks2 * 512 + kb;
            f32x4 acc = mmk_c<16>(ap, wp);
            if (ks2 == 1) {
                s_red[tile][drow + 0][lr] = acc[0]; s_red[tile][drow + 1][lr] = acc[1];
                s_red[tile][drow + 2][lr] = acc[2]; s_red[tile][drow + 3][lr] = acc[3];
            }
            __syncthreads();
            if (ks2 == 0) {
                acc[0] += s_red[tile][drow + 0][lr]; acc[1] += s_red[tile][drow + 1][lr];
                acc[2] += s_red[tile][drow + 2][lr]; acc[3] += s_red[tile][drow + 3][lr];
                int n = colb + lr;
                float xv[4], hv[4] = {0.f, 0.f, 0.f, 0.f};
                #pragma unroll
                for (int rr = 0; rr < 4; ++rr) {
                    int b = rowb + drow + rr;
                    CLOADF(xv[rr], P.xpre + (size_t)(tq * 128 + b) * 3072 + gate * DH + n);
                }
                if (gate == 1) {
                    #pragma unroll
                    for (int rr = 0; rr < 4; ++rr)
                        CLOADF(hv[rr], P.h + (size_t)(rowb + drow + rr) * DH + n);
                }
                CWAIT();
                float bias = P.b0[gate * DH + n];
                #pragma unroll
                for (int rr = 0; rr < 4; ++rr) {
                    int b = rowb + drow + rr;
                    float pre = acc[rr] + xv[rr] + bias;
                    float s = 1.f / (1.f + __expf(-pre));
                    if (gate == 0) cstoref(P.fg + (size_t)b * DH + n, s);
                    else           cstoreh(P.hib + (size_t)b * DH + n, f2bf(hv[rr] * s));
                }
            }
        }
        gbar(P.bar, lg, wg); ++lg;

        // ---- Phase B: L1 z = tanh(xpre_z + (h*i) @ W0z[h-part] + b0z); h1 = (1-f)h + f z ----
        {
            int rowb = (sub >> 2) * 16, colb = band + (sub & 3) * 32 + cw * 16;
            const unsigned short* ap = P.hib + (size_t)(rowb + lr) * DH + ks4 * 256 + kb;
            const unsigned short* wp = P.W0z + (size_t)(colb + lr) * DK2 + 1024 + ks4 * 256 + kb;
            f32x4 acc = mmk_c<8>(ap, wp);
            if (ks4 != 0) {
                s_r2[cw][ks4 - 1][drow + 0][lr] = acc[0]; s_r2[cw][ks4 - 1][drow + 1][lr] = acc[1];
                s_r2[cw][ks4 - 1][drow + 2][lr] = acc[2]; s_r2[cw][ks4 - 1][drow + 3][lr] = acc[3];
            }
            __syncthreads();
            if (ks4 == 0) {
                #pragma unroll
                for (int rr = 0; rr < 4; ++rr)
                    acc[rr] += s_r2[cw][0][drow + rr][lr] + s_r2[cw][1][drow + rr][lr]
                             + s_r2[cw][2][drow + rr][lr];
                int n = colb + lr;
                float xv[4], fv[4], hv[4];
                #pragma unroll
                for (int rr = 0; rr < 4; ++rr) {
                    int b = rowb + drow + rr;
                    CLOADF(xv[rr], P.xpre + (size_t)(tq * 128 + b) * 3072 + 2 * DH + n);
                    CLOADF(fv[rr], P.fg + (size_t)b * DH + n);
                    CLOADF(hv[rr], P.h + (size_t)b * DH + n);
                }
                CWAIT();
                float bias = P.b0[2 * DH + n];
                #pragma unroll
                for (int rr = 0; rr < 4; ++rr) {
                    int b = rowb + drow + rr;
                    float pre = acc[rr] + xv[rr] + bias;
                    float z = tanhf(pre);
                    float nh = (1.f - fv[rr]) * hv[rr] + fv[rr] * z;
                    cstoref(P.h1 + (size_t)b * DH + n, nh);
                    cstoreh(P.hcat + (size_t)b * DK2 + n, f2bf(nh));
                }
            }
        }
        gbar(P.bar, lg, wg); ++lg;

        // ---- Phase C: L2 f2 = sigmoid(h1 @ Wff + b1f), i2 = sigmoid(h1 @ Wii + b1i) ----
        {
            int gate = sub >> 4, rem = sub & 15;
            int mb = rem >> 2, nbq = rem & 3;
            const unsigned short* wt = gate ? P.Wii : P.Wff;
            int wm = tile >> 1, wn = tile & 1;
            int rowb = mb * 32 + wm * 16, colb = band + nbq * 32 + wn * 16;
            const unsigned short* ap = P.hcat + (size_t)(rowb + lr) * DK2 + ks2 * 512 + kb;
            const unsigned short* wp = wt + (size_t)(colb + lr) * DH + ks2 * 512 + kb;
            f32x4 acc = mmk_c<16>(ap, wp);
            if (ks2 == 1) {
                s_red[tile][drow + 0][lr] = acc[0]; s_red[tile][drow + 1][lr] = acc[1];
                s_red[tile][drow + 2][lr] = acc[2]; s_red[tile][drow + 3][lr] = acc[3];
            }
            __syncthreads();
            if (ks2 == 0) {
                acc[0] += s_red[tile][drow + 0][lr]; acc[1] += s_red[tile][drow + 1][lr];
                acc[2] += s_red[tile][drow + 2][lr]; acc[3] += s_red[tile][drow + 3][lr];
                int n = colb + lr;
                float h1v[4] = {0.f, 0.f, 0.f, 0.f};
                if (gate == 1) {
                    #pragma unroll
                    for (int rr = 0; rr < 4; ++rr)
                        CLOADF(h1v[rr], P.h1 + (size_t)(rowb + drow + rr) * DH + n);
                }
                CWAIT();
                float bias = P.b1[gate * DH + n];
                #pragma unroll
                for (int rr = 0; rr < 4; ++rr) {
                    int b = rowb + drow + rr;
                    float pre = acc[rr] + bias;
                    float s = 1.f / (1.f + __expf(-pre));
                    if (gate == 0) cstoref(P.f2g + (size_t)b * DH + n, s);
                    else           cstoreh(P.hcat + (size_t)b * DK2 + DH + n, f2bf(h1v[rr] * s));
                }
            }
        }
        gbar(P.bar, lg, wg); ++lg;

        // ---- Phase D: z2 = tanh([h1 | h1*i2] @ W1z + b1z); h = (1-f2)h1 + f2 z2 ----
        {
            int rowb = (sub >> 2) * 16, colb = band + (sub & 3) * 32 + cw * 16;
            const unsigned short* ap = P.hcat + (size_t)(rowb + lr) * DK2 + ks4 * 512 + kb;
            const unsigned short* wp = P.W1z + (size_t)(colb + lr) * DK2 + ks4 * 512 + kb;
            f32x4 acc = mmk_c<16>(ap, wp);
            if (ks4 != 0) {
                s_r2[cw][ks4 - 1][drow + 0][lr] = acc[0]; s_r2[cw][ks4 - 1][drow + 1][lr] = acc[1];
                s_r2[cw][ks4 - 1][drow + 2][lr] = acc[2]; s_r2[cw][ks4 - 1][drow + 3][lr] = acc[3];
            }
            __syncthreads();
            if (ks4 == 0) {
                #pragma unroll
                for (int rr = 0; rr < 4; ++rr)
                    acc[rr] += s_r2[cw][0][drow + rr][lr] + s_r2[cw][1][drow + rr][lr]
                             + s_r2[cw][2][drow + rr][lr];
                int n = colb + lr;
                float f2v[4], h1v[4];
                #pragma unroll
                for (int rr = 0; rr < 4; ++rr) {
                    int b = rowb + drow + rr;
                    CLOADF(f2v[rr], P.f2g + (size_t)b * DH + n);
                    CLOADF(h1v[rr], P.h1 + (size_t)b * DH + n);
                }
                CWAIT();
                float bias = P.b1[2 * DH + n];
                #pragma unroll
                for (int rr = 0; rr < 4; ++rr) {
                    int b = rowb + drow + rr;
                    float pre = acc[rr] + bias;
                    float z = tanhf(pre);
                    float nh = (1.f - f2v[rr]) * h1v[rr] + f2v[rr] * z;
                    cstoref(P.h + (size_t)b * DH + n, nh);
                    cstoreh(P.hb + (size_t)b * DH + n, f2bf(nh));
                    if (t == TSEQ - 1) P.out[(size_t)b * DH + n] = nh;  // normal store: kernel-end flush
                }
            }
        }
        gbar(P.bar, lg, wg); ++lg;
    }
}

extern "C" void kernel_launch(void* const* d_in, const int* in_sizes, int n_in,
                              void* d_out, int out_size, void* d_ws, size_t ws_size,
                              hipStream_t stream) {
    const float* x  = (const float*)d_in[0];
    const float* W0 = (const float*)d_in[1];
    const float* b0 = (const float*)d_in[2];
    const float* W1 = (const float*)d_in[3];
    const float* b1 = (const float*)d_in[4];

    char* ws = (char*)d_ws;
    size_t off = 0;
    auto alloc = [&](size_t bytes) { void* p = ws + off; off += (bytes + 255) & ~(size_t)255; return p; };

    unsigned short* W0f = (unsigned short*)alloc((size_t)DH * DK2 * 2);
    unsigned short* W0i = (unsigned short*)alloc((size_t)DH * DK2 * 2);
    unsigned short* W0z = (unsigned short*)alloc((size_t)DH * DK2 * 2);
    unsigned short* W1z = (unsigned short*)alloc((size_t)DH * DK2 * 2);
    unsigned short* Wff = (unsigned short*)alloc((size_t)DH * DH * 2);
    unsigned short* Wii = (unsigned short*)alloc((size_t)DH * DH * 2);
    float* xpre = (float*)alloc((size_t)32 * 128 * 3072 * 4);
    float* h    = (float*)alloc((size_t)BB * DH * 4);
    unsigned short* hb = (unsigned short*)alloc((size_t)BB * DH * 2);
    float* fg   = (float*)alloc((size_t)BB * DH * 4);
    unsigned short* hib = (unsigned short*)alloc((size_t)BB * DH * 2);
    float* h1   = (float*)alloc((size_t)BB * DH * 4);
    unsigned short* hcat = (unsigned short*)alloc((size_t)BB * DK2 * 2);
    float* f2g  = (float*)alloc((size_t)BB * DH * 4);
    int* bar    = (int*)alloc(8192);
    (void)ws_size; (void)in_sizes; (void)n_in; (void)out_size;

    prep_weights<<<10304, 256, 0, stream>>>(W0, W1, W0f, W0i, W0z, Wff, Wii, W1z,
                                            h, hb, bar);

    GruParams p;
    p.x = x; p.b0 = b0; p.b1 = b1;
    p.W0f = W0f; p.W0i = W0i; p.W0z = W0z; p.Wff = Wff; p.Wii = Wii; p.W1z = W1z;
    p.xpre = xpre; p.h = h; p.hb = hb; p.fg = fg; p.hib = hib;
    p.h1 = h1; p.hcat = hcat; p.f2g = f2g;
    p.out = (float*)d_out;
    p.bar = bar;

    void* args[] = { &p };
    hipLaunchCooperativeKernel((const void*)gru_main, dim3(NWG), dim3(NTHR), args, 0, stream);
}

// Round 8
// 15807.549 us; speedup vs baseline: 2.7254x; 1.0041x over previous
//
#include <hip/hip_runtime.h>

#define BB    128     // batch
#define TSEQ  256     // time steps
#define DH    1024    // hidden
#define DK2   2048    // concat K
#define NWG   256
#define NTHR  512

typedef __attribute__((ext_vector_type(8))) short short8;
typedef __attribute__((ext_vector_type(4))) float f32x4;

__device__ __forceinline__ unsigned short f2bf(float f) {
    union { float f; unsigned int u; } v; v.f = f;
    unsigned int r = (v.u + 0x7FFFu + ((v.u >> 16) & 1u)) >> 16;  // RNE
    return (unsigned short)r;
}

__device__ __forceinline__ int imin2(int a, int b) { return a < b ? a : b; }

// ---- coherent (device-scope) memory ops: bypass L1/L2 via sc0 sc1 ----
__device__ __forceinline__ void cstoref(float* p, float v) {
    asm volatile("global_store_dword %0, %1, off sc0 sc1" :: "v"(p), "v"(v) : "memory");
}
__device__ __forceinline__ void cstoreh(unsigned short* p, unsigned short v) {
    unsigned int w = v;
    asm volatile("global_store_short %0, %1, off sc0 sc1" :: "v"(p), "v"(w) : "memory");
}
#define CLOADF(dst, ptr) \
    asm volatile("global_load_dword %0, %1, off sc0 sc1" : "=v"(dst) : "v"(ptr))
#define CWAIT() do { asm volatile("s_waitcnt vmcnt(0)" ::: "memory"); \
                     __builtin_amdgcn_sched_barrier(0); } while (0)

// ---- grid barrier: per-WG flag store + all-poll (ZERO atomics) ----
// flags[wg] lives at bar + wg*16 (one 64B line per WG -> fully parallel
// arrival stores, no RMW serialization). Monotonic phase numbers (lg+1).
// Wave 0 of each WG polls all 256 flags (4 coherent dwords/lane) and
// min-reduces across the wave; uniform break; __syncthreads releases the WG.
// Ordering chain is identical to the R4-proven one: all-wave vmcnt(0) drain
// -> s_barrier -> signal store; observer sees ALL flags at lg+1 => every
// WG's data stores retired (per-wave program order) before its flag store.
__device__ __forceinline__ void gbar(int* bar, int lg, int wg) {
    asm volatile("s_waitcnt vmcnt(0)" ::: "memory");   // all waves: drain asm stores
    __syncthreads();
    const int tid = threadIdx.x;
    if (tid == 0) {
        int* fp = bar + wg * 16;
        int v = lg + 1;
        asm volatile("global_store_dword %0, %1, off sc0 sc1" :: "v"(fp), "v"(v) : "memory");
    }
    if (tid < 64) {
        const int* f0 = bar + (tid +   0) * 16;
        const int* f1 = bar + (tid +  64) * 16;
        const int* f2 = bar + (tid + 128) * 16;
        const int* f3 = bar + (tid + 192) * 16;
        const int target = lg + 1;
        for (;;) {
            int a, b, c, d;
            asm volatile("global_load_dword %0, %1, off sc0 sc1" : "=v"(a) : "v"(f0) : "memory");
            asm volatile("global_load_dword %0, %1, off sc0 sc1" : "=v"(b) : "v"(f1) : "memory");
            asm volatile("global_load_dword %0, %1, off sc0 sc1" : "=v"(c) : "v"(f2) : "memory");
            asm volatile("global_load_dword %0, %1, off sc0 sc1" : "=v"(d) : "v"(f3) : "memory");
            asm volatile("s_waitcnt vmcnt(0)" ::: "memory");
            int m = imin2(imin2(a, b), imin2(c, d));
            #pragma unroll
            for (int off = 32; off >= 1; off >>= 1)
                m = imin2(m, __shfl_xor(m, off, 64));
            if (__builtin_amdgcn_readfirstlane(m) >= target) break;
            __builtin_amdgcn_s_sleep(1);
        }
    }
    __syncthreads();
}

// ---------------- weight prep + state init ----------------
__global__ __launch_bounds__(256) void prep_weights(const float* __restrict__ W0,
                                                    const float* __restrict__ W1,
                                                    unsigned short* W0f, unsigned short* W0i,
                                                    unsigned short* W0z, unsigned short* Wff,
                                                    unsigned short* Wii, unsigned short* W1z,
                                                    float* h, unsigned short* hb,
                                                    int* bar) {
    int job = blockIdx.x;
    if (job >= 10240) {                     // h, hb zero-init
        int i0 = (job - 10240) * 2048 + threadIdx.x;
        #pragma unroll
        for (int k = 0; k < 8; ++k) { int i = i0 + k * 256; h[i] = 0.f; hb[i] = 0; }
        return;
    }
    if (job == 0) {
        for (int i = threadIdx.x; i < 4096; i += 256) bar[i] = 0;
    }
    __shared__ float tl[32][33];
    const int tx = threadIdx.x & 31, ty = threadIdx.x >> 5;
    if (job < 6144) {                       // W0 gates: 3 x [2048 x 1024] transpose
        int g = job >> 11, r = job & 2047, kt = r >> 5, nt = r & 31;
        const float* src = W0 + (size_t)g * DK2 * DH;
        unsigned short* dst = (g == 0) ? W0f : ((g == 1) ? W0i : W0z);
        #pragma unroll
        for (int i = 0; i < 4; ++i)
            tl[ty + i * 8][tx] = src[(size_t)(kt * 32 + ty + i * 8) * DH + nt * 32 + tx];
        __syncthreads();
        #pragma unroll
        for (int i = 0; i < 4; ++i)
            dst[(size_t)(nt * 32 + ty + i * 8) * DK2 + kt * 32 + tx] = f2bf(tl[tx][ty + i * 8]);
    } else if (job < 8192) {                // W1 f,i folded: [1024][1024]
        int r = job - 6144; int g = r >> 10; r &= 1023;
        int kt = r >> 5, nt = r & 31;
        const float* src = W1 + (size_t)g * DK2 * DH;
        unsigned short* dst = (g == 0) ? Wff : Wii;
        #pragma unroll
        for (int i = 0; i < 4; ++i)
            tl[ty + i * 8][tx] = src[(size_t)(kt * 32 + ty + i * 8) * DH + nt * 32 + tx]
                               + src[(size_t)(1024 + kt * 32 + ty + i * 8) * DH + nt * 32 + tx];
        __syncthreads();
        #pragma unroll
        for (int i = 0; i < 4; ++i)
            dst[(size_t)(nt * 32 + ty + i * 8) * DH + kt * 32 + tx] = f2bf(tl[tx][ty + i * 8]);
    } else {                                // W1 z: [2048 x 1024] transpose
        int r = job - 8192; int kt = r >> 5, nt = r & 31;
        const float* src = W1 + (size_t)2 * DK2 * DH;
        #pragma unroll
        for (int i = 0; i < 4; ++i)
            tl[ty + i * 8][tx] = src[(size_t)(kt * 32 + ty + i * 8) * DH + nt * 32 + tx];
        __syncthreads();
        #pragma unroll
        for (int i = 0; i < 4; ++i)
            W1z[(size_t)(nt * 32 + ty + i * 8) * DK2 + kt * 32 + tx] = f2bf(tl[tx][ty + i * 8]);
    }
}

// ---------------- main persistent kernel ----------------
struct GruParams {
    const float* x;
    const float* b0;
    const float* b1;
    const unsigned short* W0f;      // [1024 n][2048 k]
    const unsigned short* W0i;
    const unsigned short* W0z;
    const unsigned short* Wff;      // [1024][1024] folded
    const unsigned short* Wii;
    const unsigned short* W1z;      // [1024 n][2048 k]
    float* xpre;                    // [32][128][3072] f32 (coherent)
    float* h;  unsigned short* hb;
    float* fg;
    unsigned short* hib;
    float* h1;
    unsigned short* hcat;           // [128][2048] bf16: [h1 | h1*i2]
    float* f2g;
    float* out;
    int* bar;
};

// A-operand (activations) loaded coherently, issue-all-then-wait; weights via
// normal cached loads inside the phase (R4-proven structure).
template<int ITERS>
__device__ __forceinline__ f32x4 mmk_c(const unsigned short* __restrict__ ap,
                                       const unsigned short* __restrict__ wp) {
    short8 a[ITERS];
    short8 bw[ITERS];
    #pragma unroll
    for (int k = 0; k < ITERS; ++k)
        asm volatile("global_load_dwordx4 %0, %1, off sc0 sc1"
                     : "=v"(a[k]) : "v"(ap + (size_t)k * 32));
    #pragma unroll
    for (int k = 0; k < ITERS; ++k)
        bw[k] = *(const short8*)(wp + (size_t)k * 32);
    asm volatile("s_waitcnt vmcnt(0)" ::: "memory");
    __builtin_amdgcn_sched_barrier(0);
    f32x4 acc = {0.f, 0.f, 0.f, 0.f};
    #pragma unroll
    for (int k = 0; k < ITERS; ++k)
        acc = __builtin_amdgcn_mfma_f32_16x16x32_bf16(a[k], bw[k], acc, 0, 0, 0);
    return acc;
}

__global__ __launch_bounds__(NTHR) void gru_main(GruParams P) {
    const int wg   = blockIdx.x;
    const int xcd  = wg & 7;           // measured round-robin WG->XCD [m09]; perf-only assumption
    const int sub  = wg >> 3;          // 0..31 within XCD
    const int tid  = threadIdx.x;
    const int lane = tid & 63;
    const int wv   = tid >> 6;         // 0..7
    const int tile = wv & 3, ks2 = wv >> 2;   // 32x32 tiles: 4 sub-tiles x 2-way ksplit
    const int cw   = wv & 1, ks4 = wv >> 1;   // 16x32 tiles: 2 col-tiles x 4-way ksplit
    const int lr   = lane & 15;
    const int kb   = (lane >> 4) * 8;  // k-offset within frag
    const int drow = (lane >> 4) * 4;  // D-frag row base

    __shared__ float s_red[4][16][17];     // 32x32 phases (A, C) — +1 pad kills 4-way bank conflict
    __shared__ float s_r2[2][3][16][17];   // 16x32 phases (B, D)

    int lg = 0;

    // XCD column band: this WG only ever touches weight columns [xcd*128, xcd*128+128)
    const int band = xcd * 128;

    for (int t = 0; t < TSEQ; ++t) {
        // ---- chunk GEMM every 32 steps (XCD-banded): xpre[tt][b][g*1024+n], n in band ----
        if ((t & 31) == 0) {
            for (int j = sub; j < 192; j += 32) {
                int mb = j / 6, cj = j % 6;            // mb = tt, cj = col-job (3 gates x 2 halves)
                int g = cj >> 1, off = (cj & 1) * 64;
                int col0 = band + off;                 // within gate panel [0,1024)
                int b = wv * 16 + lr;
                const float* xp = P.x + ((size_t)b * TSEQ + (t + mb)) * DH + kb;
                const unsigned short* wt = (g == 0) ? P.W0f : ((g == 1) ? P.W0i : P.W0z);
                const unsigned short* wp = wt + (size_t)(col0 + lr) * DK2 + kb;
                f32x4 a0 = {0,0,0,0}, a1 = a0, a2 = a0, a3 = a0;
                #pragma unroll 2
                for (int k = 0; k < DH; k += 32) {
                    f32x4 lo = *(const f32x4*)(xp + k);
                    f32x4 hi = *(const f32x4*)(xp + k + 4);
                    short8 av;
                    av[0] = (short)f2bf(lo[0]); av[1] = (short)f2bf(lo[1]);
                    av[2] = (short)f2bf(lo[2]); av[3] = (short)f2bf(lo[3]);
                    av[4] = (short)f2bf(hi[0]); av[5] = (short)f2bf(hi[1]);
                    av[6] = (short)f2bf(hi[2]); av[7] = (short)f2bf(hi[3]);
                    short8 b0v = *(const short8*)(wp + k);
                    short8 b1v = *(const short8*)(wp + (size_t)16 * DK2 + k);
                    short8 b2v = *(const short8*)(wp + (size_t)32 * DK2 + k);
                    short8 b3v = *(const short8*)(wp + (size_t)48 * DK2 + k);
                    a0 = __builtin_amdgcn_mfma_f32_16x16x32_bf16(av, b0v, a0, 0, 0, 0);
                    a1 = __builtin_amdgcn_mfma_f32_16x16x32_bf16(av, b1v, a1, 0, 0, 0);
                    a2 = __builtin_amdgcn_mfma_f32_16x16x32_bf16(av, b2v, a2, 0, 0, 0);
                    a3 = __builtin_amdgcn_mfma_f32_16x16x32_bf16(av, b3v, a3, 0, 0, 0);
                }
                int rowb = mb * 128 + wv * 16 + drow;
                #pragma unroll
                for (int cf = 0; cf < 4; ++cf) {
                    f32x4 acc = (cf == 0) ? a0 : ((cf == 1) ? a1 : ((cf == 2) ? a2 : a3));
                    int col = g * DH + col0 + cf * 16 + lr;
                    #pragma unroll
                    for (int rr = 0; rr < 4; ++rr)
                        cstoref(P.xpre + (size_t)(rowb + rr) * 3072 + col, acc[rr]);
                }
            }
            gbar(P.bar, lg, wg); ++lg;
        }
        const int tq = t & 31;

        // ---- Phase A: L1 f,i = sigmoid(xpre + h @ W0{f,i}[h-part] + b0) ----
        {
            int gate = sub >> 4, rem = sub & 15;       // 2 gates x 16 tiles per XCD
            int mb = rem >> 2, nbq = rem & 3;
            const unsigned short* wt = gate ? P.W0i : P.W0f;
            int wm = tile >> 1, wn = tile & 1;
            int rowb = mb * 32 + wm * 16, colb = band + nbq * 32 + wn * 16;
            const unsigned short* ap = P.hb + (size_t)(rowb + lr) * DH + ks2 * 512 + kb;
            const unsigned short* wp = wt + (size_t)(colb + lr) * DK2 + 1024 + ks2 * 512 + kb;
            f32x4 acc = mmk_c<16>(ap, wp);
            if (ks2 == 1) {
                s_red[tile][drow + 0][lr] = acc[0]; s_red[tile][drow + 1][lr] = acc[1];
                s_red[tile][drow + 2][lr] = acc[2]; s_red[tile][drow + 3][lr] = acc[3];
            }
            __syncthreads();
            if (ks2 == 0) {
                acc[0] += s_red[tile][drow + 0][lr]; acc[1] += s_red[tile][drow + 1][lr];
                acc[2] += s_red[tile][drow + 2][lr]; acc[3] += s_red[tile][drow + 3][lr];
                int n = colb + lr;
                float xv[4], hv[4] = {0.f, 0.f, 0.f, 0.f};
                #pragma unroll
                for (int rr = 0; rr < 4; ++rr) {
                    int b = rowb + drow + rr;
                    CLOADF(xv[rr], P.xpre + (size_t)(tq * 128 + b) * 3072 + gate * DH + n);
                }
                if (gate == 1) {
                    #pragma unroll
                    for (int rr = 0; rr < 4; ++rr)
                        CLOADF(hv[rr], P.h + (size_t)(rowb + drow + rr) * DH + n);
                }
                CWAIT();
                float bias = P.b0[gate * DH + n];
                #pragma unroll
                for (int rr = 0; rr < 4; ++rr) {
                    int b = rowb + drow + rr;
                    float pre = acc[rr] + xv[rr] + bias;
                    float s = 1.f / (1.f + __expf(-pre));
                    if (gate == 0) cstoref(P.fg + (size_t)b * DH + n, s);
                    else           cstoreh(P.hib + (size_t)b * DH + n, f2bf(hv[rr] * s));
                }
            }
            gbar(P.bar, lg, wg); ++lg;
        }

        // ---- Phase B: L1 z = tanh(xpre_z + (h*i) @ W0z[h-part] + b0z); h1 = (1-f)h + f z ----
        {
            int rowb = (sub >> 2) * 16, colb = band + (sub & 3) * 32 + cw * 16;
            const unsigned short* ap = P.hib + (size_t)(rowb + lr) * DH + ks4 * 256 + kb;
            const unsigned short* wp = P.W0z + (size_t)(colb + lr) * DK2 + 1024 + ks4 * 256 + kb;
            f32x4 acc = mmk_c<8>(ap, wp);
            if (ks4 != 0) {
                s_r2[cw][ks4 - 1][drow + 0][lr] = acc[0]; s_r2[cw][ks4 - 1][drow + 1][lr] = acc[1];
                s_r2[cw][ks4 - 1][drow + 2][lr] = acc[2]; s_r2[cw][ks4 - 1][drow + 3][lr] = acc[3];
            }
            __syncthreads();
            if (ks4 == 0) {
                #pragma unroll
                for (int rr = 0; rr < 4; ++rr)
                    acc[rr] += s_r2[cw][0][drow + rr][lr] + s_r2[cw][1][drow + rr][lr]
                             + s_r2[cw][2][drow + rr][lr];
                int n = colb + lr;
                float xv[4], fv[4], hv[4];
                #pragma unroll
                for (int rr = 0; rr < 4; ++rr) {
                    int b = rowb + drow + rr;
                    CLOADF(xv[rr], P.xpre + (size_t)(tq * 128 + b) * 3072 + 2 * DH + n);
                    CLOADF(fv[rr], P.fg + (size_t)b * DH + n);
                    CLOADF(hv[rr], P.h + (size_t)b * DH + n);
                }
                CWAIT();
                float bias = P.b0[2 * DH + n];
                #pragma unroll
                for (int rr = 0; rr < 4; ++rr) {
                    int b = rowb + drow + rr;
                    float pre = acc[rr] + xv[rr] + bias;
                    float z = tanhf(pre);
                    float nh = (1.f - fv[rr]) * hv[rr] + fv[rr] * z;
                    cstoref(P.h1 + (size_t)b * DH + n, nh);
                    cstoreh(P.hcat + (size_t)b * DK2 + n, f2bf(nh));
                }
            }
            gbar(P.bar, lg, wg); ++lg;
        }

        // ---- Phase C: L2 f2 = sigmoid(h1 @ Wff + b1f), i2 = sigmoid(h1 @ Wii + b1i) ----
        {
            int gate = sub >> 4, rem = sub & 15;
            int mb = rem >> 2, nbq = rem & 3;
            const unsigned short* wt = gate ? P.Wii : P.Wff;
            int wm = tile >> 1, wn = tile & 1;
            int rowb = mb * 32 + wm * 16, colb = band + nbq * 32 + wn * 16;
            const unsigned short* ap = P.hcat + (size_t)(rowb + lr) * DK2 + ks2 * 512 + kb;
            const unsigned short* wp = wt + (size_t)(colb + lr) * DH + ks2 * 512 + kb;
            f32x4 acc = mmk_c<16>(ap, wp);
            if (ks2 == 1) {
                s_red[tile][drow + 0][lr] = acc[0]; s_red[tile][drow + 1][lr] = acc[1];
                s_red[tile][drow + 2][lr] = acc[2]; s_red[tile][drow + 3][lr] = acc[3];
            }
            __syncthreads();
            if (ks2 == 0) {
                acc[0] += s_red[tile][drow + 0][lr]; acc[1] += s_red[tile][drow + 1][lr];
                acc[2] += s_red[tile][drow + 2][lr]; acc[3] += s_red[tile][drow + 3][lr];
                int n = colb + lr;
                float h1v[4] = {0.f, 0.f, 0.f, 0.f};
                if (gate == 1) {
                    #pragma unroll
                    for (int rr = 0; rr < 4; ++rr)
                        CLOADF(h1v[rr], P.h1 + (size_t)(rowb + drow + rr) * DH + n);
                }
                CWAIT();
                float bias = P.b1[gate * DH + n];
                #pragma unroll
                for (int rr = 0; rr < 4; ++rr) {
                    int b = rowb + drow + rr;
                    float pre = acc[rr] + bias;
                    float s = 1.f / (1.f + __expf(-pre));
                    if (gate == 0) cstoref(P.f2g + (size_t)b * DH + n, s);
                    else           cstoreh(P.hcat + (size_t)b * DK2 + DH + n, f2bf(h1v[rr] * s));
                }
            }
            gbar(P.bar, lg, wg); ++lg;
        }

        // ---- Phase D: z2 = tanh([h1 | h1*i2] @ W1z + b1z); h = (1-f2)h1 + f2 z2 ----
        {
            int rowb = (sub >> 2) * 16, colb = band + (sub & 3) * 32 + cw * 16;
            const unsigned short* ap = P.hcat + (size_t)(rowb + lr) * DK2 + ks4 * 512 + kb;
            const unsigned short* wp = P.W1z + (size_t)(colb + lr) * DK2 + ks4 * 512 + kb;
            f32x4 acc = mmk_c<16>(ap, wp);
            if (ks4 != 0) {
                s_r2[cw][ks4 - 1][drow + 0][lr] = acc[0]; s_r2[cw][ks4 - 1][drow + 1][lr] = acc[1];
                s_r2[cw][ks4 - 1][drow + 2][lr] = acc[2]; s_r2[cw][ks4 - 1][drow + 3][lr] = acc[3];
            }
            __syncthreads();
            if (ks4 == 0) {
                #pragma unroll
                for (int rr = 0; rr < 4; ++rr)
                    acc[rr] += s_r2[cw][0][drow + rr][lr] + s_r2[cw][1][drow + rr][lr]
                             + s_r2[cw][2][drow + rr][lr];
                int n = colb + lr;
                float f2v[4], h1v[4];
                #pragma unroll
                for (int rr = 0; rr < 4; ++rr) {
                    int b = rowb + drow + rr;
                    CLOADF(f2v[rr], P.f2g + (size_t)b * DH + n);
                    CLOADF(h1v[rr], P.h1 + (size_t)b * DH + n);
                }
                CWAIT();
                float bias = P.b1[2 * DH + n];
                #pragma unroll
                for (int rr = 0; rr < 4; ++rr) {
                    int b = rowb + drow + rr;
                    float pre = acc[rr] + bias;
                    float z = tanhf(pre);
                    float nh = (1.f - f2v[rr]) * h1v[rr] + f2v[rr] * z;
                    cstoref(P.h + (size_t)b * DH + n, nh);
                    cstoreh(P.hb + (size_t)b * DH + n, f2bf(nh));
                    if (t == TSEQ - 1) P.out[(size_t)b * DH + n] = nh;  // normal store: kernel-end flush
                }
            }
            gbar(P.bar, lg, wg); ++lg;
        }
    }
}

extern "C" void kernel_launch(void* const* d_in, const int* in_sizes, int n_in,
                              void* d_out, int out_size, void* d_ws, size_t ws_size,
                              hipStream_t stream) {
    const float* x  = (const float*)d_in[0];
    const float* W0 = (const float*)d_in[1];
    const float* b0 = (const float*)d_in[2];
    const float* W1 = (const float*)d_in[3];
    const float* b1 = (const float*)d_in[4];

    char* ws = (char*)d_ws;
    size_t off = 0;
    auto alloc = [&](size_t bytes) { void* p = ws + off; off += (bytes + 255) & ~(size_t)255; return p; };

    unsigned short* W0f = (unsigned short*)alloc((size_t)DH * DK2 * 2);
    unsigned short* W0i = (unsigned short*)alloc((size_t)DH * DK2 * 2);
    unsigned short* W0z = (unsigned short*)alloc((size_t)DH * DK2 * 2);
    unsigned short* W1z = (unsigned short*)alloc((size_t)DH * DK2 * 2);
    unsigned short* Wff = (unsigned short*)alloc((size_t)DH * DH * 2);
    unsigned short* Wii = (unsigned short*)alloc((size_t)DH * DH * 2);
    float* xpre = (float*)alloc((size_t)32 * 128 * 3072 * 4);
    float* h    = (float*)alloc((size_t)BB * DH * 4);
    unsigned short* hb = (unsigned short*)alloc((size_t)BB * DH * 2);
    float* fg   = (float*)alloc((size_t)BB * DH * 4);
    unsigned short* hib = (unsigned short*)alloc((size_t)BB * DH * 2);
    float* h1   = (float*)alloc((size_t)BB * DH * 4);
    unsigned short* hcat = (unsigned short*)alloc((size_t)BB * DK2 * 2);
    float* f2g  = (float*)alloc((size_t)BB * DH * 4);
    int* bar    = (int*)alloc(16384);
    (void)ws_size; (void)in_sizes; (void)n_in; (void)out_size;

    prep_weights<<<10304, 256, 0, stream>>>(W0, W1, W0f, W0i, W0z, Wff, Wii, W1z,
                                            h, hb, bar);

    GruParams p;
    p.x = x; p.b0 = b0; p.b1 = b1;
    p.W0f = W0f; p.W0i = W0i; p.W0z = W0z; p.Wff = Wff; p.Wii = Wii; p.W1z = W1z;
    p.xpre = xpre; p.h = h; p.hb = hb; p.fg = fg; p.hib = hib;
    p.h1 = h1; p.hcat = hcat; p.f2g = f2g;
    p.out = (float*)d_out;
    p.bar = bar;

    void* args[] = { &p };
    hipLaunchCooperativeKernel((const void*)gru_main, dim3(NWG), dim3(NTHR), args, 0, stream);
}

// Round 10
// 15011.789 us; speedup vs baseline: 2.8699x; 1.0530x over previous
//
#include <hip/hip_runtime.h>

#define BB    128     // batch
#define TSEQ  256     // time steps
#define DH    1024    // hidden
#define DK2   2048    // concat K
#define NWG   256
#define NTHR  512

typedef __attribute__((ext_vector_type(8))) short short8;
typedef __attribute__((ext_vector_type(4))) float f32x4;

__device__ __forceinline__ unsigned short f2bf(float f) {
    union { float f; unsigned int u; } v; v.f = f;
    unsigned int r = (v.u + 0x7FFFu + ((v.u >> 16) & 1u)) >> 16;  // RNE
    return (unsigned short)r;
}

__device__ __forceinline__ int imin2(int a, int b) { return a < b ? a : b; }

#define MFMA(a, b, c) __builtin_amdgcn_mfma_f32_16x16x32_bf16((a), (b), (c), 0, 0, 0)

// ---- coherent (device-scope) memory ops: bypass L1/L2 via sc0 sc1 ----
__device__ __forceinline__ void cstoref(float* p, float v) {
    asm volatile("global_store_dword %0, %1, off sc0 sc1" :: "v"(p), "v"(v) : "memory");
}
__device__ __forceinline__ void cstoreh(unsigned short* p, unsigned short v) {
    unsigned int w = v;
    asm volatile("global_store_short %0, %1, off sc0 sc1" :: "v"(p), "v"(w) : "memory");
}
#define CLOADF(dst, ptr) \
    asm volatile("global_load_dword %0, %1, off sc0 sc1" : "=v"(dst) : "v"(ptr))
#define CLOADX4(dst, ptr) \
    asm volatile("global_load_dwordx4 %0, %1, off sc0 sc1" : "=v"(dst) : "v"(ptr))
#define CWAIT() do { asm volatile("s_waitcnt vmcnt(0)" ::: "memory"); \
                     __builtin_amdgcn_sched_barrier(0); } while (0)

// ---- grid barrier: per-WG flag store + all-poll (ZERO atomics) — R8-proven ----
__device__ __forceinline__ void gbar(int* bar, int lg, int wg) {
    asm volatile("s_waitcnt vmcnt(0)" ::: "memory");   // all waves: drain asm stores
    __syncthreads();
    const int tid = threadIdx.x;
    if (tid == 0) {
        int* fp = bar + wg * 16;
        int v = lg + 1;
        asm volatile("global_store_dword %0, %1, off sc0 sc1" :: "v"(fp), "v"(v) : "memory");
    }
    if (tid < 64) {
        const int* f0 = bar + (tid +   0) * 16;
        const int* f1 = bar + (tid +  64) * 16;
        const int* f2 = bar + (tid + 128) * 16;
        const int* f3 = bar + (tid + 192) * 16;
        const int target = lg + 1;
        for (;;) {
            int a, b, c, d;
            asm volatile("global_load_dword %0, %1, off sc0 sc1" : "=v"(a) : "v"(f0) : "memory");
            asm volatile("global_load_dword %0, %1, off sc0 sc1" : "=v"(b) : "v"(f1) : "memory");
            asm volatile("global_load_dword %0, %1, off sc0 sc1" : "=v"(c) : "v"(f2) : "memory");
            asm volatile("global_load_dword %0, %1, off sc0 sc1" : "=v"(d) : "v"(f3) : "memory");
            asm volatile("s_waitcnt vmcnt(0)" ::: "memory");
            int m = imin2(imin2(a, b), imin2(c, d));
            #pragma unroll
            for (int off = 32; off >= 1; off >>= 1)
                m = imin2(m, __shfl_xor(m, off, 64));
            if (__builtin_amdgcn_readfirstlane(m) >= target) break;
            __builtin_amdgcn_s_sleep(1);
        }
    }
    __syncthreads();
}

// ---------------- weight prep + state init ----------------
__global__ __launch_bounds__(256) void prep_weights(const float* __restrict__ W0,
                                                    const float* __restrict__ W1,
                                                    unsigned short* W0f, unsigned short* W0i,
                                                    unsigned short* W0z, unsigned short* Wff,
                                                    unsigned short* Wii, unsigned short* W1z,
                                                    float* h, unsigned short* hb,
                                                    int* bar) {
    int job = blockIdx.x;
    if (job >= 10240) {                     // h, hb zero-init
        int i0 = (job - 10240) * 2048 + threadIdx.x;
        #pragma unroll
        for (int k = 0; k < 8; ++k) { int i = i0 + k * 256; h[i] = 0.f; hb[i] = 0; }
        return;
    }
    if (job == 0) {
        for (int i = threadIdx.x; i < 4096; i += 256) bar[i] = 0;
    }
    __shared__ float tl[32][33];
    const int tx = threadIdx.x & 31, ty = threadIdx.x >> 5;
    if (job < 6144) {                       // W0 gates: 3 x [2048 x 1024] transpose
        int g = job >> 11, r = job & 2047, kt = r >> 5, nt = r & 31;
        const float* src = W0 + (size_t)g * DK2 * DH;
        unsigned short* dst = (g == 0) ? W0f : ((g == 1) ? W0i : W0z);
        #pragma unroll
        for (int i = 0; i < 4; ++i)
            tl[ty + i * 8][tx] = src[(size_t)(kt * 32 + ty + i * 8) * DH + nt * 32 + tx];
        __syncthreads();
        #pragma unroll
        for (int i = 0; i < 4; ++i)
            dst[(size_t)(nt * 32 + ty + i * 8) * DK2 + kt * 32 + tx] = f2bf(tl[tx][ty + i * 8]);
    } else if (job < 8192) {                // W1 f,i folded: [1024][1024]
        int r = job - 6144; int g = r >> 10; r &= 1023;
        int kt = r >> 5, nt = r & 31;
        const float* src = W1 + (size_t)g * DK2 * DH;
        unsigned short* dst = (g == 0) ? Wff : Wii;
        #pragma unroll
        for (int i = 0; i < 4; ++i)
            tl[ty + i * 8][tx] = src[(size_t)(kt * 32 + ty + i * 8) * DH + nt * 32 + tx]
                               + src[(size_t)(1024 + kt * 32 + ty + i * 8) * DH + nt * 32 + tx];
        __syncthreads();
        #pragma unroll
        for (int i = 0; i < 4; ++i)
            dst[(size_t)(nt * 32 + ty + i * 8) * DH + kt * 32 + tx] = f2bf(tl[tx][ty + i * 8]);
    } else {                                // W1 z: [2048 x 1024] transpose
        int r = job - 8192; int kt = r >> 5, nt = r & 31;
        const float* src = W1 + (size_t)2 * DK2 * DH;
        #pragma unroll
        for (int i = 0; i < 4; ++i)
            tl[ty + i * 8][tx] = src[(size_t)(kt * 32 + ty + i * 8) * DH + nt * 32 + tx];
        __syncthreads();
        #pragma unroll
        for (int i = 0; i < 4; ++i)
            W1z[(size_t)(nt * 32 + ty + i * 8) * DK2 + kt * 32 + tx] = f2bf(tl[tx][ty + i * 8]);
    }
}

// ---------------- main persistent kernel ----------------
struct GruParams {
    const float* x;
    const float* b0;
    const float* b1;
    const unsigned short* W0f;      // [1024 n][2048 k]
    const unsigned short* W0i;
    const unsigned short* W0z;
    const unsigned short* Wff;      // [1024][1024] folded
    const unsigned short* Wii;
    const unsigned short* W1z;      // [1024 n][2048 k]
    float* xpre;                    // [32][128][3072] f32 (coherent)
    float* h;  unsigned short* hb;
    float* fg;
    unsigned short* hib;
    float* h1;
    unsigned short* hcat;           // [128][2048] bf16: [h1 | h1*i2]
    float* f2g;
    float* out;
    int* bar;
};

__global__ __launch_bounds__(NTHR) void gru_main(GruParams P) {
    const int wg   = blockIdx.x;
    const int xcd  = wg & 7;
    const int sub  = wg >> 3;          // 0..31 within band
    const int tid  = threadIdx.x;
    const int lane = tid & 63;
    const int wv   = tid >> 6;         // 0..7
    const int tile = wv & 3, ks2 = wv >> 2;   // 32x32 tiles: 4 sub-tiles x 2-way ksplit
    const int cw   = wv & 1, ks4 = wv >> 1;   // 16x32 tiles: 2 col-tiles x 4-way ksplit
    const int lr   = lane & 15;
    const int kb   = (lane >> 4) * 8;  // k-offset within frag
    const int drow = (lane >> 4) * 4;  // D-frag row base

    __shared__ float s_red[4][16][17];     // 32x32 phases (A, C)
    __shared__ float s_r2[2][3][16][17];   // 16x32 phases (B, D)

    int lg = 0;
    const int band = xcd * 128;

    for (int t = 0; t < TSEQ; ++t) {
        // ---- chunk GEMM every 32 steps (XCD-banded) — unchanged from R8 ----
        if ((t & 31) == 0) {
            for (int j = sub; j < 192; j += 32) {
                int mb = j / 6, cj = j % 6;
                int g = cj >> 1, off = (cj & 1) * 64;
                int col0 = band + off;
                int b = wv * 16 + lr;
                const float* xp = P.x + ((size_t)b * TSEQ + (t + mb)) * DH + kb;
                const unsigned short* wt = (g == 0) ? P.W0f : ((g == 1) ? P.W0i : P.W0z);
                const unsigned short* wp = wt + (size_t)(col0 + lr) * DK2 + kb;
                f32x4 a0 = {0,0,0,0}, a1 = a0, a2 = a0, a3 = a0;
                #pragma unroll 2
                for (int k = 0; k < DH; k += 32) {
                    f32x4 lo = *(const f32x4*)(xp + k);
                    f32x4 hi = *(const f32x4*)(xp + k + 4);
                    short8 av;
                    av[0] = (short)f2bf(lo[0]); av[1] = (short)f2bf(lo[1]);
                    av[2] = (short)f2bf(lo[2]); av[3] = (short)f2bf(lo[3]);
                    av[4] = (short)f2bf(hi[0]); av[5] = (short)f2bf(hi[1]);
                    av[6] = (short)f2bf(hi[2]); av[7] = (short)f2bf(hi[3]);
                    short8 b0v = *(const short8*)(wp + k);
                    short8 b1v = *(const short8*)(wp + (size_t)16 * DK2 + k);
                    short8 b2v = *(const short8*)(wp + (size_t)32 * DK2 + k);
                    short8 b3v = *(const short8*)(wp + (size_t)48 * DK2 + k);
                    a0 = MFMA(av, b0v, a0);
                    a1 = MFMA(av, b1v, a1);
                    a2 = MFMA(av, b2v, a2);
                    a3 = MFMA(av, b3v, a3);
                }
                int rowb = mb * 128 + wv * 16 + drow;
                #pragma unroll
                for (int cf = 0; cf < 4; ++cf) {
                    f32x4 acc = (cf == 0) ? a0 : ((cf == 1) ? a1 : ((cf == 2) ? a2 : a3));
                    int col = g * DH + col0 + cf * 16 + lr;
                    #pragma unroll
                    for (int rr = 0; rr < 4; ++rr)
                        cstoref(P.xpre + (size_t)(rowb + rr) * 3072 + col, acc[rr]);
                }
            }
            gbar(P.bar, lg, wg); ++lg;
        }
        const int tq = t & 31;

        // ---- Phase A: L1 f,i = sigmoid(xpre + h @ W0{f,i}[h-part] + b0) ----
        // CHANGE vs R8: epilogue coherent loads (xv, hv) issued AT PHASE ENTRY,
        // covered by the single CWAIT — removes the second round-trip.
        {
            int gate = sub >> 4, rem = sub & 15;
            int mb = rem >> 2, nbq = rem & 3;
            const unsigned short* wt = gate ? P.W0i : P.W0f;
            int wm = tile >> 1, wn = tile & 1;
            int rowb = mb * 32 + wm * 16, colb = band + nbq * 32 + wn * 16;
            const unsigned short* ap = P.hb + (size_t)(rowb + lr) * DH + ks2 * 512 + kb;
            const unsigned short* wp = wt + (size_t)(colb + lr) * DK2 + 1024 + ks2 * 512 + kb;
            int n = colb + lr;
            short8 a[16];
            #pragma unroll
            for (int k = 0; k < 16; ++k) CLOADX4(a[k], ap + (size_t)k * 32);
            float xv[4] = {0,0,0,0}, hv[4] = {0,0,0,0};
            if (ks2 == 0) {
                #pragma unroll
                for (int rr = 0; rr < 4; ++rr)
                    CLOADF(xv[rr], P.xpre + (size_t)(tq * 128 + rowb + drow + rr) * 3072 + gate * DH + n);
                if (gate == 1) {
                    #pragma unroll
                    for (int rr = 0; rr < 4; ++rr)
                        CLOADF(hv[rr], P.h + (size_t)(rowb + drow + rr) * DH + n);
                }
            }
            short8 bw[16];
            #pragma unroll
            for (int k = 0; k < 16; ++k) bw[k] = *(const short8*)(wp + (size_t)k * 32);
            CWAIT();
            f32x4 acc = {0.f, 0.f, 0.f, 0.f};
            #pragma unroll
            for (int k = 0; k < 16; ++k) acc = MFMA(a[k], bw[k], acc);
            if (ks2 == 1) {
                s_red[tile][drow + 0][lr] = acc[0]; s_red[tile][drow + 1][lr] = acc[1];
                s_red[tile][drow + 2][lr] = acc[2]; s_red[tile][drow + 3][lr] = acc[3];
            }
            __syncthreads();
            if (ks2 == 0) {
                acc[0] += s_red[tile][drow + 0][lr]; acc[1] += s_red[tile][drow + 1][lr];
                acc[2] += s_red[tile][drow + 2][lr]; acc[3] += s_red[tile][drow + 3][lr];
                float bias = P.b0[gate * DH + n];
                #pragma unroll
                for (int rr = 0; rr < 4; ++rr) {
                    int b = rowb + drow + rr;
                    float pre = acc[rr] + xv[rr] + bias;
                    float s = 1.f / (1.f + __expf(-pre));
                    if (gate == 0) cstoref(P.fg + (size_t)b * DH + n, s);
                    else           cstoreh(P.hib + (size_t)b * DH + n, f2bf(hv[rr] * s));
                }
            }
            gbar(P.bar, lg, wg); ++lg;
        }

        // ---- Phase B: L1 z = tanh(xpre_z + (h*i) @ W0z[h-part] + b0z); h1 = (1-f)h + f z ----
        {
            int rowb = (sub >> 2) * 16, colb = band + (sub & 3) * 32 + cw * 16;
            const unsigned short* ap = P.hib + (size_t)(rowb + lr) * DH + ks4 * 256 + kb;
            const unsigned short* wp = P.W0z + (size_t)(colb + lr) * DK2 + 1024 + ks4 * 256 + kb;
            int n = colb + lr;
            short8 a[8];
            #pragma unroll
            for (int k = 0; k < 8; ++k) CLOADX4(a[k], ap + (size_t)k * 32);
            float xv[4] = {0,0,0,0}, fv[4] = {0,0,0,0}, hv[4] = {0,0,0,0};
            if (ks4 == 0) {
                #pragma unroll
                for (int rr = 0; rr < 4; ++rr) {
                    int b = rowb + drow + rr;
                    CLOADF(xv[rr], P.xpre + (size_t)(tq * 128 + b) * 3072 + 2 * DH + n);
                    CLOADF(fv[rr], P.fg + (size_t)b * DH + n);
                    CLOADF(hv[rr], P.h + (size_t)b * DH + n);
                }
            }
            short8 bw[8];
            #pragma unroll
            for (int k = 0; k < 8; ++k) bw[k] = *(const short8*)(wp + (size_t)k * 32);
            CWAIT();
            f32x4 acc = {0.f, 0.f, 0.f, 0.f};
            #pragma unroll
            for (int k = 0; k < 8; ++k) acc = MFMA(a[k], bw[k], acc);
            if (ks4 != 0) {
                s_r2[cw][ks4 - 1][drow + 0][lr] = acc[0]; s_r2[cw][ks4 - 1][drow + 1][lr] = acc[1];
                s_r2[cw][ks4 - 1][drow + 2][lr] = acc[2]; s_r2[cw][ks4 - 1][drow + 3][lr] = acc[3];
            }
            __syncthreads();
            if (ks4 == 0) {
                #pragma unroll
                for (int rr = 0; rr < 4; ++rr)
                    acc[rr] += s_r2[cw][0][drow + rr][lr] + s_r2[cw][1][drow + rr][lr]
                             + s_r2[cw][2][drow + rr][lr];
                float bias = P.b0[2 * DH + n];
                #pragma unroll
                for (int rr = 0; rr < 4; ++rr) {
                    int b = rowb + drow + rr;
                    float pre = acc[rr] + xv[rr] + bias;
                    float z = tanhf(pre);
                    float nh = (1.f - fv[rr]) * hv[rr] + fv[rr] * z;
                    cstoref(P.h1 + (size_t)b * DH + n, nh);
                    cstoreh(P.hcat + (size_t)b * DK2 + n, f2bf(nh));
                }
            }
            gbar(P.bar, lg, wg); ++lg;
        }

        // ---- Phase C: L2 f2 = sigmoid(h1 @ Wff + b1f), i2 = sigmoid(h1 @ Wii + b1i) ----
        {
            int gate = sub >> 4, rem = sub & 15;
            int mb = rem >> 2, nbq = rem & 3;
            const unsigned short* wt = gate ? P.Wii : P.Wff;
            int wm = tile >> 1, wn = tile & 1;
            int rowb = mb * 32 + wm * 16, colb = band + nbq * 32 + wn * 16;
            const unsigned short* ap = P.hcat + (size_t)(rowb + lr) * DK2 + ks2 * 512 + kb;
            const unsigned short* wp = wt + (size_t)(colb + lr) * DH + ks2 * 512 + kb;
            int n = colb + lr;
            short8 a[16];
            #pragma unroll
            for (int k = 0; k < 16; ++k) CLOADX4(a[k], ap + (size_t)k * 32);
            float h1v[4] = {0,0,0,0};
            if (ks2 == 0 && gate == 1) {
                #pragma unroll
                for (int rr = 0; rr < 4; ++rr)
                    CLOADF(h1v[rr], P.h1 + (size_t)(rowb + drow + rr) * DH + n);
            }
            short8 bw[16];
            #pragma unroll
            for (int k = 0; k < 16; ++k) bw[k] = *(const short8*)(wp + (size_t)k * 32);
            CWAIT();
            f32x4 acc = {0.f, 0.f, 0.f, 0.f};
            #pragma unroll
            for (int k = 0; k < 16; ++k) acc = MFMA(a[k], bw[k], acc);
            if (ks2 == 1) {
                s_red[tile][drow + 0][lr] = acc[0]; s_red[tile][drow + 1][lr] = acc[1];
                s_red[tile][drow + 2][lr] = acc[2]; s_red[tile][drow + 3][lr] = acc[3];
            }
            __syncthreads();
            if (ks2 == 0) {
                acc[0] += s_red[tile][drow + 0][lr]; acc[1] += s_red[tile][drow + 1][lr];
                acc[2] += s_red[tile][drow + 2][lr]; acc[3] += s_red[tile][drow + 3][lr];
                float bias = P.b1[gate * DH + n];
                #pragma unroll
                for (int rr = 0; rr < 4; ++rr) {
                    int b = rowb + drow + rr;
                    float pre = acc[rr] + bias;
                    float s = 1.f / (1.f + __expf(-pre));
                    if (gate == 0) cstoref(P.f2g + (size_t)b * DH + n, s);
                    else           cstoreh(P.hcat + (size_t)b * DK2 + DH + n, f2bf(h1v[rr] * s));
                }
            }
            gbar(P.bar, lg, wg); ++lg;
        }

        // ---- Phase D: z2 = tanh([h1 | h1*i2] @ W1z + b1z); h = (1-f2)h1 + f2 z2 ----
        {
            int rowb = (sub >> 2) * 16, colb = band + (sub & 3) * 32 + cw * 16;
            const unsigned short* ap = P.hcat + (size_t)(rowb + lr) * DK2 + ks4 * 512 + kb;
            const unsigned short* wp = P.W1z + (size_t)(colb + lr) * DK2 + ks4 * 512 + kb;
            int n = colb + lr;
            short8 a[16];
            #pragma unroll
            for (int k = 0; k < 16; ++k) CLOADX4(a[k], ap + (size_t)k * 32);
            float f2v[4] = {0,0,0,0}, h1v[4] = {0,0,0,0};
            if (ks4 == 0) {
                #pragma unroll
                for (int rr = 0; rr < 4; ++rr) {
                    int b = rowb + drow + rr;
                    CLOADF(f2v[rr], P.f2g + (size_t)b * DH + n);
                    CLOADF(h1v[rr], P.h1 + (size_t)b * DH + n);
                }
            }
            short8 bw[16];
            #pragma unroll
            for (int k = 0; k < 16; ++k) bw[k] = *(const short8*)(wp + (size_t)k * 32);
            CWAIT();
            f32x4 acc = {0.f, 0.f, 0.f, 0.f};
            #pragma unroll
            for (int k = 0; k < 16; ++k) acc = MFMA(a[k], bw[k], acc);
            if (ks4 != 0) {
                s_r2[cw][ks4 - 1][drow + 0][lr] = acc[0]; s_r2[cw][ks4 - 1][drow + 1][lr] = acc[1];
                s_r2[cw][ks4 - 1][drow + 2][lr] = acc[2]; s_r2[cw][ks4 - 1][drow + 3][lr] = acc[3];
            }
            __syncthreads();
            if (ks4 == 0) {
                #pragma unroll
                for (int rr = 0; rr < 4; ++rr)
                    acc[rr] += s_r2[cw][0][drow + rr][lr] + s_r2[cw][1][drow + rr][lr]
                             + s_r2[cw][2][drow + rr][lr];
                float bias = P.b1[2 * DH + n];
                #pragma unroll
                for (int rr = 0; rr < 4; ++rr) {
                    int b = rowb + drow + rr;
                    float pre = acc[rr] + bias;
                    float z = tanhf(pre);
                    float nh = (1.f - f2v[rr]) * h1v[rr] + f2v[rr] * z;
                    cstoref(P.h + (size_t)b * DH + n, nh);
                    cstoreh(P.hb + (size_t)b * DH + n, f2bf(nh));
                    if (t == TSEQ - 1) P.out[(size_t)b * DH + n] = nh;  // normal store: kernel-end flush
                }
            }
            gbar(P.bar, lg, wg); ++lg;
        }
    }
}

extern "C" void kernel_launch(void* const* d_in, const int* in_sizes, int n_in,
                              void* d_out, int out_size, void* d_ws, size_t ws_size,
                              hipStream_t stream) {
    const float* x  = (const float*)d_in[0];
    const float* W0 = (const float*)d_in[1];
    const float* b0 = (const float*)d_in[2];
    const float* W1 = (const float*)d_in[3];
    const float* b1 = (const float*)d_in[4];

    char* ws = (char*)d_ws;
    size_t off = 0;
    auto alloc = [&](size_t bytes) { void* p = ws + off; off += (bytes + 255) & ~(size_t)255; return p; };

    unsigned short* W0f = (unsigned short*)alloc((size_t)DH * DK2 * 2);
    unsigned short* W0i = (unsigned short*)alloc((size_t)DH * DK2 * 2);
    unsigned short* W0z = (unsigned short*)alloc((size_t)DH * DK2 * 2);
    unsigned short* W1z = (unsigned short*)alloc((size_t)DH * DK2 * 2);
    unsigned short* Wff = (unsigned short*)alloc((size_t)DH * DH * 2);
    unsigned short* Wii = (unsigned short*)alloc((size_t)DH * DH * 2);
    float* xpre = (float*)alloc((size_t)32 * 128 * 3072 * 4);
    float* h    = (float*)alloc((size_t)BB * DH * 4);
    unsigned short* hb = (unsigned short*)alloc((size_t)BB * DH * 2);
    float* fg   = (float*)alloc((size_t)BB * DH * 4);
    unsigned short* hib = (unsigned short*)alloc((size_t)BB * DH * 2);
    float* h1   = (float*)alloc((size_t)BB * DH * 4);
    unsigned short* hcat = (unsigned short*)alloc((size_t)BB * DK2 * 2);
    float* f2g  = (float*)alloc((size_t)BB * DH * 4);
    int* bar    = (int*)alloc(16384);
    (void)ws_size; (void)in_sizes; (void)n_in; (void)out_size;

    prep_weights<<<10304, 256, 0, stream>>>(W0, W1, W0f, W0i, W0z, Wff, Wii, W1z,
                                            h, hb, bar);

    GruParams p;
    p.x = x; p.b0 = b0; p.b1 = b1;
    p.W0f = W0f; p.W0i = W0i; p.W0z = W0z; p.Wff = Wff; p.Wii = Wii; p.W1z = W1z;
    p.xpre = xpre; p.h = h; p.hb = hb; p.fg = fg; p.hib = hib;
    p.h1 = h1; p.hcat = hcat; p.f2g = f2g;
    p.out = (float*)d_out;
    p.bar = bar;

    void* args[] = { &p };
    hipLaunchCooperativeKernel((const void*)gru_main, dim3(NWG), dim3(NTHR), args, 0, stream);
}